// Round 22
// baseline (113.534 us; speedup 1.0000x reference)
//
#include <hip/hip_runtime.h>
#include <hip/hip_bf16.h>

typedef __bf16 bf16_t;
typedef __bf16 bf16x8 __attribute__((ext_vector_type(8)));
typedef float f32x4 __attribute__((ext_vector_type(4)));
typedef float f32x8v __attribute__((ext_vector_type(8)));

#define B_    2
#define T_    2048
#define C_    1024
#define H_    16
#define D_    64
#define M_    4096      // B*T
#define NQKV_ 3072
#define PLD   72        // attn V^T LDS row stride
#define NQT2  16        // T_/128 q-tiles (attn)
#define GTILE (128 * 64)   // proj GEMM LDS tile (elements)
#define SLOT2 32768        // qkv ring slot elements (A 128x64 + B 384x64)
#define KSB   4096         // attn Ks buffer elements (64x64)
#define VTB   (64 * PLD)   // attn Vt buffer elements

static __device__ __forceinline__ float  bf2f(bf16_t x) { return (float)x; }
static __device__ __forceinline__ bf16_t f2bf(float x)  { return (bf16_t)x; }

// async global->LDS, 16B per lane; LDS dest is wave-uniform base + lane*16 (HW rule)
typedef const __attribute__((address_space(1))) void gas_void;
typedef __attribute__((address_space(3))) void las_void;
static __device__ __forceinline__ void gld16(const void* g, void* l) {
  __builtin_amdgcn_global_load_lds((gas_void*)g, (las_void*)l, 16, 0, 0);
}

// ---------------- RoPE cos/sin table: [T][32] float2 ----------------
__global__ __launch_bounds__(256) void rope_tab_k(float2* __restrict__ tab) {
  int i = blockIdx.x * 256 + threadIdx.x;      // < T_*32
  int tpos = i >> 5, d = i & 31;
  float fr = exp2f(-(float)d * (13.287712379549449f / 32.0f));  // 10000^(-d/32)
  float ang = (float)tpos * fr;
  tab[i] = make_float2(cosf(ang), sinf(ang));
}

// ---------------- x: fp32 -> bf16 bulk convert ----------------
__global__ __launch_bounds__(256) void f32_to_bf16_k(const float* __restrict__ in,
                                                     bf16_t* __restrict__ out) {
  const int i = (blockIdx.x * 256 + threadIdx.x) * 8;
  f32x8v v = *(const f32x8v*)(in + i);
  bf16x8 h;
#pragma unroll
  for (int j = 0; j < 8; ++j) h[j] = f2bf(v[j]);
  *(bf16x8*)(out + i) = h;
}

// ---------------- transpose + fp32->bf16 (in: R x Ccols fp32 -> out: Ccols x R bf16) ----
__global__ __launch_bounds__(256) void transpose_f32_bf16(const float* __restrict__ in,
                                                          bf16_t* __restrict__ out,
                                                          int R, int Ccols) {
  __shared__ bf16_t tile[32][33];
  int tx = threadIdx.x & 31, ty = threadIdx.x >> 5;
  int c0 = blockIdx.x * 32, r0 = blockIdx.y * 32;
#pragma unroll
  for (int j = 0; j < 4; ++j)
    tile[ty + j * 8][tx] = f2bf(in[(size_t)(r0 + ty + j * 8) * Ccols + c0 + tx]);
  __syncthreads();
#pragma unroll
  for (int j = 0; j < 4; ++j)
    out[(size_t)(c0 + ty + j * 8) * R + r0 + tx] = tile[tx][ty + j * 8];
}

// ------- proj GEMM core (r11-verified): 128x128, dbuf global_load_lds, 2-barrier ----
__device__ __forceinline__ void gemm_core(const bf16_t* __restrict__ A,
                                          const bf16_t* __restrict__ Bt,
                                          int m0, int n0,
                                          bf16_t* sm,
                                          f32x4 acc[4][4]) {
  const int t    = threadIdx.x;
  const int lane = t & 63, w = t >> 6;
  const int wr = (w >> 1) * 64, wc = (w & 1) * 64;
  const int l15 = lane & 15, g4 = lane >> 4;

  const f32x4 z4 = {0.f, 0.f, 0.f, 0.f};
#pragma unroll
  for (int i = 0; i < 4; ++i)
#pragma unroll
    for (int j = 0; j < 4; ++j) acc[i][j] = z4;

  const int srow = w * 32 + (lane >> 3);
  const int sel8 = (lane & 7) * 8;
  const bf16_t* gA = A  + (size_t)(m0 + srow) * C_ + sel8;
  const bf16_t* gB = Bt + (size_t)(n0 + srow) * C_ + sel8;
  const int dOff = (w * 32) * 64;

#pragma unroll
  for (int j = 0; j < 4; ++j) {
    gld16(gA + (size_t)(j * 8) * C_, sm + dOff + j * 8 * 64);
    gld16(gB + (size_t)(j * 8) * C_, sm + GTILE + dOff + j * 8 * 64);
  }
  __syncthreads();

  int cur = 0;
  for (int kt = 0; kt < C_ / 64; ++kt) {
    if (kt + 1 < C_ / 64) {
      const int k0 = (kt + 1) * 64;
      bf16_t* nA = sm + (cur ^ 1) * (2 * GTILE);
      bf16_t* nB = nA + GTILE;
#pragma unroll
      for (int j = 0; j < 4; ++j) {
        gld16(gA + (size_t)(j * 8) * C_ + k0, nA + dOff + j * 8 * 64);
        gld16(gB + (size_t)(j * 8) * C_ + k0, nB + dOff + j * 8 * 64);
      }
    }
    const bf16_t* lA = sm + cur * (2 * GTILE);
    const bf16_t* lB = lA + GTILE;
#pragma unroll
    for (int ks = 0; ks < 2; ++ks) {
      bf16x8 af[4], bfv[4];
#pragma unroll
      for (int mi = 0; mi < 4; ++mi)
        af[mi] = *(const bf16x8*)&lA[(wr + mi * 16 + l15) * 64 + ks * 32 + g4 * 8];
#pragma unroll
      for (int ni = 0; ni < 4; ++ni)
        bfv[ni] = *(const bf16x8*)&lB[(wc + ni * 16 + l15) * 64 + ks * 32 + g4 * 8];
#pragma unroll
      for (int mi = 0; mi < 4; ++mi)
#pragma unroll
        for (int ni = 0; ni < 4; ++ni)
          acc[mi][ni] = __builtin_amdgcn_mfma_f32_16x16x32_bf16(af[mi], bfv[ni],
                                                                acc[mi][ni], 0, 0, 0);
    }
    __syncthreads();
    cur ^= 1;
  }
}

// ---- GEMM1: qkv, 128x384 tile, BK=64 2-slot ring (r21-verified, full CU coverage) ----
__global__ __launch_bounds__(512, 2) void qkv_gemm(const bf16_t* __restrict__ x,
                                                   const bf16_t* __restrict__ wT,
                                                   const float* __restrict__ bias,
                                                   const float2* __restrict__ rtab,
                                                   bf16_t* __restrict__ qo,
                                                   bf16_t* __restrict__ ko,
                                                   bf16_t* __restrict__ vo) {
  __shared__ __align__(16) bf16_t sm[2 * SLOT2];       // 128 KB ring; reused as store stage
  const int t = threadIdx.x;
  const int lane = t & 63, w = t >> 6;                 // 8 waves
  const int l15 = lane & 15, g4 = lane >> 4;
  const int wr = (w >> 1) * 32, wc = (w & 1) * 192;    // 4M x 2N -> 32x192 per wave

  const int bid = blockIdx.x;                          // 256 = 32m x 8n tiles
  const int swz = (bid & 7) * 32 + (bid >> 3);         // XCD-chunked, n-major
  const int m0 = (swz & 31) * 128, n0 = (swz >> 5) * 384;

  const f32x4 z4 = {0.f, 0.f, 0.f, 0.f};
  f32x4 acc[2][12];
#pragma unroll
  for (int i = 0; i < 2; ++i)
#pragma unroll
    for (int j = 0; j < 12; ++j) acc[i][j] = z4;

  const int sr8 = lane >> 3;
  const int swc = ((lane & 7) ^ ((lane >> 3) & 7)) * 8;
  const bf16_t* gA = x  + (size_t)(m0 + w * 16 + sr8) * C_ + swc;
  const bf16_t* gB = wT + (size_t)(n0 + w * 48 + sr8) * C_ + swc;

#define QKV_STAGE(h)                                                            \
  {                                                                             \
    bf16_t* sl = sm + ((h) & 1) * SLOT2;                                        \
    const size_t kofs = (size_t)(h) * 64;                                       \
    gld16(gA + kofs,            sl + (w * 16 +  0) * 64);                       \
    gld16(gA +  8 * C_ + kofs,  sl + (w * 16 +  8) * 64);                       \
    gld16(gB + kofs,            sl + 8192 + (w * 48 +  0) * 64);                \
    gld16(gB +  8 * C_ + kofs,  sl + 8192 + (w * 48 +  8) * 64);                \
    gld16(gB + 16 * C_ + kofs,  sl + 8192 + (w * 48 + 16) * 64);                \
    gld16(gB + 24 * C_ + kofs,  sl + 8192 + (w * 48 + 24) * 64);                \
    gld16(gB + 32 * C_ + kofs,  sl + 8192 + (w * 48 + 32) * 64);                \
    gld16(gB + 40 * C_ + kofs,  sl + 8192 + (w * 48 + 40) * 64);                \
  }

  QKV_STAGE(0);

  const int csw = l15 & 7;                // read-side swizzle bits (= row&7)

  for (int h = 0; h < 16; ++h) {
    asm volatile("s_waitcnt vmcnt(0)" ::: "memory");
    __builtin_amdgcn_sched_barrier(0);
    __builtin_amdgcn_s_barrier();
    __builtin_amdgcn_sched_barrier(0);
    if (h + 1 < 16) QKV_STAGE(h + 1);     // slot freed by the barrier above

    const bf16_t* sl = sm + (h & 1) * SLOT2;
#pragma unroll
    for (int ks = 0; ks < 2; ++ks) {
      bf16x8 af[2], bfv[12];
#pragma unroll
      for (int mi = 0; mi < 2; ++mi)
        af[mi] = *(const bf16x8*)&sl[(wr + mi * 16 + l15) * 64 + (((ks * 4 + g4) ^ csw) * 8)];
#pragma unroll
      for (int ni = 0; ni < 12; ++ni)
        bfv[ni] = *(const bf16x8*)&sl[8192 + (wc + ni * 16 + l15) * 64 + (((ks * 4 + g4) ^ csw) * 8)];
#pragma unroll
      for (int mi = 0; mi < 2; ++mi)
#pragma unroll
        for (int ni = 0; ni < 12; ++ni)
          acc[mi][ni] = __builtin_amdgcn_mfma_f32_16x16x32_bf16(af[mi], bfv[ni],
                                                                acc[mi][ni], 0, 0, 0);
    }
  }
#undef QKV_STAGE

  __syncthreads();                       // all compute done; reuse sm as store stage
  bf16_t* stg = sm + w * 6144;           // per-wave 32x192 stage (96 KB total)

#pragma unroll
  for (int cc = 0; cc < 3; ++cc) {
    const int ngc = n0 + (w & 1) * 192 + cc * 64;   // 64-aligned chunk -> single (sel, head)
    const int sel = ngc >> 10;
    if (sel < 2) {
      const float qs = (sel == 0) ? 0.125f * 1.4426950408889634f : 1.0f;
#pragma unroll
      for (int mi = 0; mi < 2; ++mi) {
#pragma unroll
        for (int nq = 0; nq < 2; ++nq) {
          const int d1 = nq * 16 + l15;        // 0..31; partner is d1+32 (frag nq+2)
          const float b1 = bias[ngc + d1];
          const float b2 = bias[ngc + d1 + 32];
#pragma unroll
          for (int r = 0; r < 4; ++r) {
            const int lrow = mi * 16 + g4 * 4 + r;
            const int tpos = (m0 + wr + lrow) & (T_ - 1);
            const float2 cs = rtab[tpos * 32 + d1];
            const float x1 = acc[mi][cc * 4 + nq][r]     + b1;
            const float x2 = acc[mi][cc * 4 + nq + 2][r] + b2;
            stg[lrow * 192 + cc * 64 + d1]      = f2bf((x1 * cs.x - x2 * cs.y) * qs);
            stg[lrow * 192 + cc * 64 + d1 + 32] = f2bf((x1 * cs.y + x2 * cs.x) * qs);
          }
        }
      }
    } else {
#pragma unroll
      for (int mi = 0; mi < 2; ++mi)
#pragma unroll
        for (int nq = 0; nq < 4; ++nq) {
          const int d = nq * 16 + l15;
          const float b1 = bias[ngc + d];
#pragma unroll
          for (int r = 0; r < 4; ++r)
            stg[(mi * 16 + g4 * 4 + r) * 192 + cc * 64 + d] = f2bf(acc[mi][cc * 4 + nq][r] + b1);
        }
    }
  }

  // readback own region (intra-wave dep only) + 1KB-per-instruction stores
  const int a  = lane >> 3;        // row-in-group 0..7
  const int b8 = (lane & 7) * 8;   // col chunk (x8 bf16 = 16B)
#pragma unroll
  for (int cc = 0; cc < 3; ++cc) {
    const int ngc = n0 + (w & 1) * 192 + cc * 64;
    const int sel = ngc >> 10;
    const int hh  = (ngc & 1023) >> 6;
    bf16_t* outp = (sel == 0) ? qo : (sel == 1 ? ko : vo);
#pragma unroll
    for (int pp = 0; pp < 4; ++pp) {
      const int lrow = pp * 8 + a;
      const int row  = m0 + wr + lrow;
      const int tpos = row & (T_ - 1);
      const int bb   = row >> 11;
      uint4 val = *(const uint4*)&stg[lrow * 192 + cc * 64 + b8];
      *(uint4*)(outp + ((size_t)(bb * H_ + hh) * T_ + tpos) * D_ + b8) = val;
    }
  }
}

// ---- flash attention, swapped-QK, T15 two-tile pipeline ----
// iter it: QK(it) [MFMA] then finish(it-1) [softmax VALU + PV MFMA] -> softmax of the
// previous tile overlaps QK MFMAs (independent). K: 2 buffers (unchanged hazards).
// V: 3 buffers (PV(it-1) reads (it-1)%3 while staging writes (it+1)%3; differ by 2 mod 3;
// write target's previous reader ran iter it-1, barrier-separated). Math sequence per
// tile identical to r18 -> bit-identical output.
__global__ __launch_bounds__(512) void attn_fwd(const bf16_t* __restrict__ q,
                                                const bf16_t* __restrict__ k,
                                                const bf16_t* __restrict__ v,
                                                bf16_t* __restrict__ y) {
  __shared__ __align__(16) bf16_t Ks[2 * KSB];         // K rows [key][d], XOR-swizzled
  __shared__ __align__(16) bf16_t Vt[3 * VTB];         // V^T [d][slot(kappa,d)] x3
  const int t = threadIdx.x;
  const int lane = t & 63, w = t >> 6;                 // w: 0..7
  const int l15 = lane & 15, g4 = lane >> 4;

  const int f   = blockIdx.x;
  const int idx = f & 255;
  const int bh  = idx & 31;
  const int p   = idx >> 5;                            // 0..7
  const int qt  = (f >> 8) ? (15 - p) : p;             // bijective over 0..15
  const int qb  = qt * 128;
  const size_t hb = (size_t)bh * T_ * D_;

  const int qrow = qb + w * 16 + l15;
  bf16x8 qf[2];
  qf[0] = *(const bf16x8*)(q + hb + (size_t)qrow * D_ + g4 * 8);
  qf[1] = *(const bf16x8*)(q + hb + (size_t)qrow * D_ + 32 + g4 * 8);

  const f32x4 z4 = {0.f, 0.f, 0.f, 0.f};
  f32x4 o[4];
#pragma unroll
  for (int i = 0; i < 4; ++i) o[i] = z4;
  float mx = -1e30f, L = 0.f;

  const int skk = t >> 3;                  // key row 0..63 (staging)
  const int sd0 = (t & 7) * 8;
  const int u   = t & 7;                   // = (d>>3)&7 for all this thread's d rows
  const int ksw = sd0 ^ ((skk & 7) * 8);   // Ks swizzled col
  // kappa slot for key=skk: slot = 32*c1 + 8*g + 4*c0 + r
  const int slot = ((skk >> 5) & 1) * 32 + ((skk >> 2) & 3) * 8 + ((skk >> 4) & 1) * 4 + (skk & 3);
  const int pos  = (((slot >> 3) ^ u) << 3) | (slot & 7);
  const int rowb = qb + w * 16 + g4 * 4;

  const int ntiles = 2 * qt + 2;

  // prologue: stage tile 0 into K buf 0, V buf 0
  {
    uint4 kv0 = *(const uint4*)(k + hb + (size_t)skk * D_ + sd0);
    uint4 vv0 = *(const uint4*)(v + hb + (size_t)skk * D_ + sd0);
    *(uint4*)&Ks[skk * 64 + ksw] = kv0;
    const bf16_t* vb = (const bf16_t*)&vv0;
#pragma unroll
    for (int i = 0; i < 8; ++i)
      Vt[(sd0 + i) * PLD + pos] = vb[i];
  }
  __syncthreads();

  f32x4 sp[4];                             // previous tile's scores (post-mask)
  bool prevValid = false;
  int kread = 0, vwr = 1, vfin = 2;        // vfin -> (it-1)%3 after first bump
  uint4 kv, vv;

  for (int it = 0; it <= ntiles; ++it) {
    const bool hasNext = (it + 1 < ntiles);
    if (hasNext) {                        // issue next tile's loads (hide under compute)
      const size_t nb = hb + (size_t)((it + 1) * 64 + skk) * D_ + sd0;
      kv = *(const uint4*)(k + nb);
      vv = *(const uint4*)(v + nb);
    }

    const bool doQK = (it < ntiles) && !((it == ntiles - 1) && w < 4);
    f32x4 sc[4];
    if (doQK) {
      const int kb = it * 64;
      const bf16_t* KsC = Ks + kread * KSB;
#pragma unroll
      for (int c = 0; c < 4; ++c) sc[c] = z4;
#pragma unroll
      for (int ks = 0; ks < 2; ++ks)
#pragma unroll
        for (int c = 0; c < 4; ++c) {
          const int kr = c * 16 + l15;
          bf16x8 kf = *(const bf16x8*)&KsC[kr * 64 + ((ks * 32 + g4 * 8) ^ ((kr & 7) * 8))];
          sc[c] = __builtin_amdgcn_mfma_f32_16x16x32_bf16(kf, qf[ks], sc[c], 0, 0, 0);
        }
      if (it == ntiles - 1 || (it == ntiles - 2 && w < 4)) {
#pragma unroll
        for (int c = 0; c < 4; ++c)
#pragma unroll
          for (int r = 0; r < 4; ++r)
            if (kb + c * 16 + g4 * 4 + r > qrow) sc[c][r] = -1e30f;
      }
    }

    if (prevValid) {                      // finish tile it-1: softmax + PV
      float tm = -1e30f;
#pragma unroll
      for (int c = 0; c < 4; ++c)
#pragma unroll
        for (int r = 0; r < 4; ++r) tm = fmaxf(tm, sp[c][r]);
      tm = fmaxf(tm, __shfl_xor(tm, 16));
      tm = fmaxf(tm, __shfl_xor(tm, 32));
      if (!__all(tm - mx <= 8.0f)) {      // wave-uniform; rare after warm-up
        const float mnew = fmaxf(mx, tm);
        const float sc2 = exp2f(mx - mnew);
        L *= sc2;
        float scr[4];
#pragma unroll
        for (int r = 0; r < 4; ++r)
          scr[r] = __shfl(sc2, (lane & 48) | (g4 * 4 + r));
#pragma unroll
        for (int nf = 0; nf < 4; ++nf)
#pragma unroll
          for (int r = 0; r < 4; ++r) o[nf][r] *= scr[r];
        mx = mnew;
      }
      float rs = 0.f;
#pragma unroll
      for (int c = 0; c < 4; ++c)
#pragma unroll
        for (int r = 0; r < 4; ++r) {
          sp[c][r] = exp2f(sp[c][r] - mx);  // bounded by 2^8
          rs += sp[c][r];
        }
      rs += __shfl_xor(rs, 16);
      rs += __shfl_xor(rs, 32);
      L += rs;

      bf16x8 ap0, ap1;
#pragma unroll
      for (int r = 0; r < 4; ++r) {
        ap0[r]     = f2bf(sp[0][r]);
        ap0[4 + r] = f2bf(sp[1][r]);
        ap1[r]     = f2bf(sp[2][r]);
        ap1[4 + r] = f2bf(sp[3][r]);
      }
      const bf16_t* VtC = Vt + vfin * VTB;
#pragma unroll
      for (int nf = 0; nf < 4; ++nf) {
        const int d  = nf * 16 + l15;
        const int h3 = (2 * nf + (l15 >> 3)) & 7;   // (d>>3)&7
        bf16x8 vf0 = *(const bf16x8*)&VtC[d * PLD + ((g4 ^ h3) << 3)];
        bf16x8 vf1 = *(const bf16x8*)&VtC[d * PLD + (((g4 + 4) ^ h3) << 3)];
        o[nf] = __builtin_amdgcn_mfma_f32_16x16x32_bf16(ap0, vf0, o[nf], 0, 0, 0);
        o[nf] = __builtin_amdgcn_mfma_f32_16x16x32_bf16(ap1, vf1, o[nf], 0, 0, 0);
      }
    }

    if (doQK) {
#pragma unroll
      for (int c = 0; c < 4; ++c) sp[c] = sc[c];
    }
    prevValid = doQK;

    if (hasNext) {                        // write prefetched tile: K buf kread^1, V buf vwr
      bf16_t* KsN = Ks + (kread ^ 1) * KSB;
      bf16_t* VtN = Vt + vwr * VTB;
      *(uint4*)&KsN[skk * 64 + ksw] = kv;
      const bf16_t* vb = (const bf16_t*)&vv;
#pragma unroll
      for (int i = 0; i < 8; ++i)
        VtN[(sd0 + i) * PLD + pos] = vb[i];
    }
    if (it < ntiles) __syncthreads();

    kread ^= 1;
    vwr  = (vwr  == 2) ? 0 : vwr + 1;
    vfin = (vfin == 2) ? 0 : vfin + 1;
  }

  const int bb = bh / H_, hh = bh % H_;
  float il[4];
#pragma unroll
  for (int r = 0; r < 4; ++r)
    il[r] = 1.0f / __shfl(L, (lane & 48) | (g4 * 4 + r));
#pragma unroll
  for (int nf = 0; nf < 4; ++nf)
#pragma unroll
    for (int r = 0; r < 4; ++r) {
      const int row = rowb + r;
      y[(size_t)(bb * T_ + row) * C_ + hh * D_ + nf * 16 + l15] = f2bf(o[nf][r] * il[r]);
    }
}

// ---------------- GEMM2: out = y @ w_proj + b_proj (fp32 out) ----------------
// 1D grid + XCD swizzle (256 = 8 XCD x 32; one n-tile per XCD)
__global__ __launch_bounds__(256) void proj_gemm(const bf16_t* __restrict__ yin,
                                                 const bf16_t* __restrict__ wT,
                                                 const float* __restrict__ bias,
                                                 float* __restrict__ out) {
  __shared__ __align__(16) bf16_t smem[4 * GTILE];
  f32x4 acc[4][4];
  const int bid = blockIdx.x;
  const int swz = (bid & 7) * 32 + (bid >> 3);
  const int m0 = (swz & 31) * 128, n0 = (swz >> 5) * 128;
  gemm_core(yin, wT, m0, n0, smem, acc);

  const int t = threadIdx.x;
  const int lane = t & 63, w = t >> 6;
  const int wr = (w >> 1) * 64, wc = (w & 1) * 64;
  const int l15 = lane & 15, g4 = lane >> 4;
  const int ng = n0 + wc;
#pragma unroll
  for (int mi = 0; mi < 4; ++mi) {
    const int rowb = m0 + wr + mi * 16 + g4 * 4;
#pragma unroll
    for (int ni = 0; ni < 4; ++ni) {
      const int n = ng + ni * 16 + l15;
      const float b1 = bias[n];
#pragma unroll
      for (int r = 0; r < 4; ++r)
        out[(size_t)(rowb + r) * C_ + n] = acc[mi][ni][r] + b1;
    }
  }
}

// ---------------- launch ----------------
extern "C" void kernel_launch(void* const* d_in, const int* in_sizes, int n_in,
                              void* d_out, int out_size, void* d_ws, size_t ws_size,
                              hipStream_t stream) {
  (void)in_sizes; (void)n_in; (void)out_size; (void)ws_size;
  const float* x      = (const float*)d_in[0];
  const float* w_attn = (const float*)d_in[1];
  const float* b_attn = (const float*)d_in[2];
  const float* w_proj = (const float*)d_in[3];
  const float* b_proj = (const float*)d_in[4];
  float* out = (float*)d_out;

  char* ws = (char*)d_ws;
  bf16_t* wTa = (bf16_t*)ws;  ws += (size_t)NQKV_ * C_ * 2;          // 6 MB
  bf16_t* wTp = (bf16_t*)ws;  ws += (size_t)C_ * C_ * 2;             // 2 MB
  bf16_t* qb  = (bf16_t*)ws;  ws += (size_t)B_ * H_ * T_ * D_ * 2;   // 8 MB
  bf16_t* kb  = (bf16_t*)ws;  ws += (size_t)B_ * H_ * T_ * D_ * 2;   // 8 MB
  bf16_t* vb  = (bf16_t*)ws;  ws += (size_t)B_ * H_ * T_ * D_ * 2;   // 8 MB
  bf16_t* yb  = (bf16_t*)ws;  ws += (size_t)B_ * T_ * C_ * 2;        // 8 MB
  float2* rtab = (float2*)ws; ws += (size_t)T_ * 32 * sizeof(float2);// 0.5 MB
  // x_bf aliases yb: x_bf is consumed by qkv_gemm (dispatch 4) strictly before
  // attn_fwd (dispatch 5) writes yb. Stream-ordered, deterministic.
  bf16_t* x_bf = yb;

  rope_tab_k<<<dim3(T_ * 32 / 256), 256, 0, stream>>>(rtab);
  transpose_f32_bf16<<<dim3(NQKV_ / 32, C_ / 32), 256, 0, stream>>>(w_attn, wTa, C_, NQKV_);
  transpose_f32_bf16<<<dim3(C_ / 32,   C_ / 32), 256, 0, stream>>>(w_proj, wTp, C_, C_);
  f32_to_bf16_k<<<dim3(M_ * C_ / (256 * 8)), 256, 0, stream>>>(x, x_bf);
  qkv_gemm<<<dim3((M_ / 128) * (NQKV_ / 384)), 512, 0, stream>>>(x_bf, wTa, b_attn, rtab, qb, kb, vb);
  attn_fwd<<<dim3(NQT2 * 32), 512, 0, stream>>>(qb, kb, vb, yb);
  proj_gemm<<<dim3((M_ / 128) * (C_ / 128)), 256, 0, stream>>>(yb, wTp, b_proj, out);
}

// Round 23
// 104.349 us; speedup vs baseline: 1.0880x; 1.0880x over previous
//
#include <hip/hip_runtime.h>
#include <hip/hip_bf16.h>

typedef __bf16 bf16_t;
typedef __bf16 bf16x8 __attribute__((ext_vector_type(8)));
typedef float f32x4 __attribute__((ext_vector_type(4)));
typedef float f32x8v __attribute__((ext_vector_type(8)));

#define B_    2
#define T_    2048
#define C_    1024
#define H_    16
#define D_    64
#define M_    4096      // B*T
#define NQKV_ 3072
#define PLD   72        // attn V^T LDS row stride
#define NQT2  16        // T_/128 q-tiles (attn)
#define GTILE (128 * 64)   // proj GEMM LDS tile (elements)
#define SLOT2 32768        // qkv ring slot elements (A 128x64 + B 384x64)
#define KSB   4096         // attn Ks buffer elements (64x64)
#define VTB   (64 * PLD)   // attn Vt buffer elements

static __device__ __forceinline__ float  bf2f(bf16_t x) { return (float)x; }
static __device__ __forceinline__ bf16_t f2bf(float x)  { return (bf16_t)x; }

// async global->LDS, 16B per lane; LDS dest is wave-uniform base + lane*16 (HW rule)
typedef const __attribute__((address_space(1))) void gas_void;
typedef __attribute__((address_space(3))) void las_void;
static __device__ __forceinline__ void gld16(const void* g, void* l) {
  __builtin_amdgcn_global_load_lds((gas_void*)g, (las_void*)l, 16, 0, 0);
}

// ---- fused prep: rope table | w_attn transpose | w_proj transpose | x->bf16 ----
// Independent jobs, dispatched by block range (uniform per-block branch).
__global__ __launch_bounds__(256) void prep_k(float2* __restrict__ rtab,
                                              const float* __restrict__ w_attn,
                                              bf16_t* __restrict__ wTa,
                                              const float* __restrict__ w_proj,
                                              bf16_t* __restrict__ wTp,
                                              const float* __restrict__ x,
                                              bf16_t* __restrict__ x_bf) {
  __shared__ bf16_t tile[32][33];
  const int bid = blockIdx.x;

  if (bid < 256) {                       // rope table: [T][32] float2
    int i = bid * 256 + threadIdx.x;
    int tpos = i >> 5, d = i & 31;
    float fr = exp2f(-(float)d * (13.287712379549449f / 32.0f));
    float ang = (float)tpos * fr;
    rtab[i] = make_float2(cosf(ang), sinf(ang));
    return;
  }
  if (bid < 256 + 3072) {                // transpose w_attn (C_ x NQKV_) -> wTa
    const int id = bid - 256;
    const int c0 = (id % 96) * 32, r0 = (id / 96) * 32;
    const int tx = threadIdx.x & 31, ty = threadIdx.x >> 5;
#pragma unroll
    for (int j = 0; j < 4; ++j)
      tile[ty + j * 8][tx] = f2bf(w_attn[(size_t)(r0 + ty + j * 8) * NQKV_ + c0 + tx]);
    __syncthreads();
#pragma unroll
    for (int j = 0; j < 4; ++j)
      wTa[(size_t)(c0 + ty + j * 8) * C_ + r0 + tx] = tile[tx][ty + j * 8];
    return;
  }
  if (bid < 256 + 3072 + 1024) {         // transpose w_proj (C_ x C_) -> wTp
    const int id = bid - (256 + 3072);
    const int c0 = (id % 32) * 32, r0 = (id / 32) * 32;
    const int tx = threadIdx.x & 31, ty = threadIdx.x >> 5;
#pragma unroll
    for (int j = 0; j < 4; ++j)
      tile[ty + j * 8][tx] = f2bf(w_proj[(size_t)(r0 + ty + j * 8) * C_ + c0 + tx]);
    __syncthreads();
#pragma unroll
    for (int j = 0; j < 4; ++j)
      wTp[(size_t)(c0 + ty + j * 8) * C_ + r0 + tx] = tile[tx][ty + j * 8];
    return;
  }
  {                                      // x fp32 -> bf16 (2048 blocks)
    const int id = bid - (256 + 3072 + 1024);
    const int i = (id * 256 + threadIdx.x) * 8;
    f32x8v v = *(const f32x8v*)(x + i);
    bf16x8 h;
#pragma unroll
    for (int j = 0; j < 8; ++j) h[j] = f2bf(v[j]);
    *(bf16x8*)(x_bf + i) = h;
  }
}

// ------- proj GEMM core (r11-verified): 128x128, dbuf global_load_lds, 2-barrier ----
__device__ __forceinline__ void gemm_core(const bf16_t* __restrict__ A,
                                          const bf16_t* __restrict__ Bt,
                                          int m0, int n0,
                                          bf16_t* sm,
                                          f32x4 acc[4][4]) {
  const int t    = threadIdx.x;
  const int lane = t & 63, w = t >> 6;
  const int wr = (w >> 1) * 64, wc = (w & 1) * 64;
  const int l15 = lane & 15, g4 = lane >> 4;

  const f32x4 z4 = {0.f, 0.f, 0.f, 0.f};
#pragma unroll
  for (int i = 0; i < 4; ++i)
#pragma unroll
    for (int j = 0; j < 4; ++j) acc[i][j] = z4;

  const int srow = w * 32 + (lane >> 3);
  const int sel8 = (lane & 7) * 8;
  const bf16_t* gA = A  + (size_t)(m0 + srow) * C_ + sel8;
  const bf16_t* gB = Bt + (size_t)(n0 + srow) * C_ + sel8;
  const int dOff = (w * 32) * 64;

#pragma unroll
  for (int j = 0; j < 4; ++j) {
    gld16(gA + (size_t)(j * 8) * C_, sm + dOff + j * 8 * 64);
    gld16(gB + (size_t)(j * 8) * C_, sm + GTILE + dOff + j * 8 * 64);
  }
  __syncthreads();

  int cur = 0;
  for (int kt = 0; kt < C_ / 64; ++kt) {
    if (kt + 1 < C_ / 64) {
      const int k0 = (kt + 1) * 64;
      bf16_t* nA = sm + (cur ^ 1) * (2 * GTILE);
      bf16_t* nB = nA + GTILE;
#pragma unroll
      for (int j = 0; j < 4; ++j) {
        gld16(gA + (size_t)(j * 8) * C_ + k0, nA + dOff + j * 8 * 64);
        gld16(gB + (size_t)(j * 8) * C_ + k0, nB + dOff + j * 8 * 64);
      }
    }
    const bf16_t* lA = sm + cur * (2 * GTILE);
    const bf16_t* lB = lA + GTILE;
#pragma unroll
    for (int ks = 0; ks < 2; ++ks) {
      bf16x8 af[4], bfv[4];
#pragma unroll
      for (int mi = 0; mi < 4; ++mi)
        af[mi] = *(const bf16x8*)&lA[(wr + mi * 16 + l15) * 64 + ks * 32 + g4 * 8];
#pragma unroll
      for (int ni = 0; ni < 4; ++ni)
        bfv[ni] = *(const bf16x8*)&lB[(wc + ni * 16 + l15) * 64 + ks * 32 + g4 * 8];
#pragma unroll
      for (int mi = 0; mi < 4; ++mi)
#pragma unroll
        for (int ni = 0; ni < 4; ++ni)
          acc[mi][ni] = __builtin_amdgcn_mfma_f32_16x16x32_bf16(af[mi], bfv[ni],
                                                                acc[mi][ni], 0, 0, 0);
    }
    __syncthreads();
    cur ^= 1;
  }
}

// ---- GEMM1: qkv, 128x384 tile, BK=64 2-slot ring (r21-verified, full CU coverage) ----
__global__ __launch_bounds__(512, 2) void qkv_gemm(const bf16_t* __restrict__ x,
                                                   const bf16_t* __restrict__ wT,
                                                   const float* __restrict__ bias,
                                                   const float2* __restrict__ rtab,
                                                   bf16_t* __restrict__ qo,
                                                   bf16_t* __restrict__ ko,
                                                   bf16_t* __restrict__ vo) {
  __shared__ __align__(16) bf16_t sm[2 * SLOT2];       // 128 KB ring; reused as store stage
  const int t = threadIdx.x;
  const int lane = t & 63, w = t >> 6;                 // 8 waves
  const int l15 = lane & 15, g4 = lane >> 4;
  const int wr = (w >> 1) * 32, wc = (w & 1) * 192;    // 4M x 2N -> 32x192 per wave

  const int bid = blockIdx.x;                          // 256 = 32m x 8n tiles
  const int swz = (bid & 7) * 32 + (bid >> 3);         // XCD-chunked, n-major
  const int m0 = (swz & 31) * 128, n0 = (swz >> 5) * 384;

  const f32x4 z4 = {0.f, 0.f, 0.f, 0.f};
  f32x4 acc[2][12];
#pragma unroll
  for (int i = 0; i < 2; ++i)
#pragma unroll
    for (int j = 0; j < 12; ++j) acc[i][j] = z4;

  const int sr8 = lane >> 3;
  const int swc = ((lane & 7) ^ ((lane >> 3) & 7)) * 8;
  const bf16_t* gA = x  + (size_t)(m0 + w * 16 + sr8) * C_ + swc;
  const bf16_t* gB = wT + (size_t)(n0 + w * 48 + sr8) * C_ + swc;

#define QKV_STAGE(h)                                                            \
  {                                                                             \
    bf16_t* sl = sm + ((h) & 1) * SLOT2;                                        \
    const size_t kofs = (size_t)(h) * 64;                                       \
    gld16(gA + kofs,            sl + (w * 16 +  0) * 64);                       \
    gld16(gA +  8 * C_ + kofs,  sl + (w * 16 +  8) * 64);                       \
    gld16(gB + kofs,            sl + 8192 + (w * 48 +  0) * 64);                \
    gld16(gB +  8 * C_ + kofs,  sl + 8192 + (w * 48 +  8) * 64);                \
    gld16(gB + 16 * C_ + kofs,  sl + 8192 + (w * 48 + 16) * 64);                \
    gld16(gB + 24 * C_ + kofs,  sl + 8192 + (w * 48 + 24) * 64);                \
    gld16(gB + 32 * C_ + kofs,  sl + 8192 + (w * 48 + 32) * 64);                \
    gld16(gB + 40 * C_ + kofs,  sl + 8192 + (w * 48 + 40) * 64);                \
  }

  QKV_STAGE(0);

  const int csw = l15 & 7;                // read-side swizzle bits (= row&7)

  for (int h = 0; h < 16; ++h) {
    asm volatile("s_waitcnt vmcnt(0)" ::: "memory");
    __builtin_amdgcn_sched_barrier(0);
    __builtin_amdgcn_s_barrier();
    __builtin_amdgcn_sched_barrier(0);
    if (h + 1 < 16) QKV_STAGE(h + 1);     // slot freed by the barrier above

    const bf16_t* sl = sm + (h & 1) * SLOT2;
#pragma unroll
    for (int ks = 0; ks < 2; ++ks) {
      bf16x8 af[2], bfv[12];
#pragma unroll
      for (int mi = 0; mi < 2; ++mi)
        af[mi] = *(const bf16x8*)&sl[(wr + mi * 16 + l15) * 64 + (((ks * 4 + g4) ^ csw) * 8)];
#pragma unroll
      for (int ni = 0; ni < 12; ++ni)
        bfv[ni] = *(const bf16x8*)&sl[8192 + (wc + ni * 16 + l15) * 64 + (((ks * 4 + g4) ^ csw) * 8)];
#pragma unroll
      for (int mi = 0; mi < 2; ++mi)
#pragma unroll
        for (int ni = 0; ni < 12; ++ni)
          acc[mi][ni] = __builtin_amdgcn_mfma_f32_16x16x32_bf16(af[mi], bfv[ni],
                                                                acc[mi][ni], 0, 0, 0);
    }
  }
#undef QKV_STAGE

  __syncthreads();                       // all compute done; reuse sm as store stage
  bf16_t* stg = sm + w * 6144;           // per-wave 32x192 stage (96 KB total)

#pragma unroll
  for (int cc = 0; cc < 3; ++cc) {
    const int ngc = n0 + (w & 1) * 192 + cc * 64;   // 64-aligned chunk -> single (sel, head)
    const int sel = ngc >> 10;
    if (sel < 2) {
      const float qs = (sel == 0) ? 0.125f * 1.4426950408889634f : 1.0f;
#pragma unroll
      for (int mi = 0; mi < 2; ++mi) {
#pragma unroll
        for (int nq = 0; nq < 2; ++nq) {
          const int d1 = nq * 16 + l15;        // 0..31; partner is d1+32 (frag nq+2)
          const float b1 = bias[ngc + d1];
          const float b2 = bias[ngc + d1 + 32];
#pragma unroll
          for (int r = 0; r < 4; ++r) {
            const int lrow = mi * 16 + g4 * 4 + r;
            const int tpos = (m0 + wr + lrow) & (T_ - 1);
            const float2 cs = rtab[tpos * 32 + d1];
            const float x1 = acc[mi][cc * 4 + nq][r]     + b1;
            const float x2 = acc[mi][cc * 4 + nq + 2][r] + b2;
            stg[lrow * 192 + cc * 64 + d1]      = f2bf((x1 * cs.x - x2 * cs.y) * qs);
            stg[lrow * 192 + cc * 64 + d1 + 32] = f2bf((x1 * cs.y + x2 * cs.x) * qs);
          }
        }
      }
    } else {
#pragma unroll
      for (int mi = 0; mi < 2; ++mi)
#pragma unroll
        for (int nq = 0; nq < 4; ++nq) {
          const int d = nq * 16 + l15;
          const float b1 = bias[ngc + d];
#pragma unroll
          for (int r = 0; r < 4; ++r)
            stg[(mi * 16 + g4 * 4 + r) * 192 + cc * 64 + d] = f2bf(acc[mi][cc * 4 + nq][r] + b1);
        }
    }
  }

  // readback own region (intra-wave dep only) + 1KB-per-instruction stores
  const int a  = lane >> 3;        // row-in-group 0..7
  const int b8 = (lane & 7) * 8;   // col chunk (x8 bf16 = 16B)
#pragma unroll
  for (int cc = 0; cc < 3; ++cc) {
    const int ngc = n0 + (w & 1) * 192 + cc * 64;
    const int sel = ngc >> 10;
    const int hh  = (ngc & 1023) >> 6;
    bf16_t* outp = (sel == 0) ? qo : (sel == 1 ? ko : vo);
#pragma unroll
    for (int pp = 0; pp < 4; ++pp) {
      const int lrow = pp * 8 + a;
      const int row  = m0 + wr + lrow;
      const int tpos = row & (T_ - 1);
      const int bb   = row >> 11;
      uint4 val = *(const uint4*)&stg[lrow * 192 + cc * 64 + b8];
      *(uint4*)(outp + ((size_t)(bb * H_ + hh) * T_ + tpos) * D_ + b8) = val;
    }
  }
}

// ---- flash attention, swapped-QK: 128 q-rows (8 waves x 16), KBLK=64 ----
// (r18-exact: K/V LDS dbuf, one barrier/tile, 50.8 us verified. r22's T15 two-tile
//  pipeline regressed to ~54 — +12 VGPR / extra state outweighed overlap; m253 null.)
__global__ __launch_bounds__(512) void attn_fwd(const bf16_t* __restrict__ q,
                                                const bf16_t* __restrict__ k,
                                                const bf16_t* __restrict__ v,
                                                bf16_t* __restrict__ y) {
  __shared__ __align__(16) bf16_t Ks[2 * KSB];         // K rows [key][d], XOR-swizzled
  __shared__ __align__(16) bf16_t Vt[2 * VTB];         // V^T [d][slot(kappa,d)]
  const int t = threadIdx.x;
  const int lane = t & 63, w = t >> 6;                 // w: 0..7
  const int l15 = lane & 15, g4 = lane >> 4;

  const int f   = blockIdx.x;
  const int idx = f & 255;
  const int bh  = idx & 31;
  const int p   = idx >> 5;                            // 0..7
  const int qt  = (f >> 8) ? (15 - p) : p;             // bijective over 0..15
  const int qb  = qt * 128;
  const size_t hb = (size_t)bh * T_ * D_;

  const int qrow = qb + w * 16 + l15;
  bf16x8 qf[2];
  qf[0] = *(const bf16x8*)(q + hb + (size_t)qrow * D_ + g4 * 8);
  qf[1] = *(const bf16x8*)(q + hb + (size_t)qrow * D_ + 32 + g4 * 8);

  const f32x4 z4 = {0.f, 0.f, 0.f, 0.f};
  f32x4 o[4];
#pragma unroll
  for (int i = 0; i < 4; ++i) o[i] = z4;
  float mx = -1e30f, L = 0.f;

  const int skk = t >> 3;                  // key row 0..63 (full tile, one pass)
  const int sd0 = (t & 7) * 8;
  const int u   = t & 7;                   // = (d>>3)&7 for all this thread's d rows
  const int ksw = sd0 ^ ((skk & 7) * 8);   // Ks swizzled col
  // kappa slot for key=skk: slot = 32*c1 + 8*g + 4*c0 + r
  const int slot = ((skk >> 5) & 1) * 32 + ((skk >> 2) & 3) * 8 + ((skk >> 4) & 1) * 4 + (skk & 3);
  const int pos  = (((slot >> 3) ^ u) << 3) | (slot & 7);
  const int rowb = qb + w * 16 + g4 * 4;

  const int ntiles = 2 * qt + 2;

  // prologue: stage tile 0 into buffer 0
  {
    uint4 kv0 = *(const uint4*)(k + hb + (size_t)skk * D_ + sd0);
    uint4 vv0 = *(const uint4*)(v + hb + (size_t)skk * D_ + sd0);
    *(uint4*)&Ks[skk * 64 + ksw] = kv0;
    const bf16_t* vb = (const bf16_t*)&vv0;
#pragma unroll
    for (int i = 0; i < 8; ++i)
      Vt[(sd0 + i) * PLD + pos] = vb[i];
  }
  __syncthreads();

  uint4 kv, vv;
  for (int it = 0; it < ntiles; ++it) {
    const int kb  = it * 64;
    const int cur = it & 1;
    const bool last = (it == ntiles - 1);

    if (it + 1 < ntiles) {                // issue next tile's loads (hide under compute)
      const size_t nb = hb + (size_t)(kb + 64 + skk) * D_ + sd0;
      kv = *(const uint4*)(k + nb);
      vv = *(const uint4*)(v + nb);
    }

    if (!(last && w < 4)) {               // fully-masked tile: skip compute only
      const bf16_t* KsC = Ks + cur * KSB;
      const bf16_t* VtC = Vt + cur * VTB;

      // ---- QK^T swapped: s[c][r] = S[key=kb+c*16+g4*4+r][q=qrow] ----
      f32x4 s[4];
#pragma unroll
      for (int c = 0; c < 4; ++c) s[c] = z4;
#pragma unroll
      for (int ks = 0; ks < 2; ++ks)
#pragma unroll
        for (int c = 0; c < 4; ++c) {
          const int kr = c * 16 + l15;
          bf16x8 kf = *(const bf16x8*)&KsC[kr * 64 + ((ks * 32 + g4 * 8) ^ ((kr & 7) * 8))];
          s[c] = __builtin_amdgcn_mfma_f32_16x16x32_bf16(kf, qf[ks], s[c], 0, 0, 0);
        }

      // ---- causal mask: only the two diagonal-adjacent tiles can violate ----
      if (last || (it == ntiles - 2 && w < 4)) {
#pragma unroll
        for (int c = 0; c < 4; ++c)
#pragma unroll
          for (int r = 0; r < 4; ++r)
            if (kb + c * 16 + g4 * 4 + r > qrow) s[c][r] = -1e30f;
      }

      // ---- online softmax (exp2 domain; defer-max THR=8) ----
      float tm = -1e30f;
#pragma unroll
      for (int c = 0; c < 4; ++c)
#pragma unroll
        for (int r = 0; r < 4; ++r) tm = fmaxf(tm, s[c][r]);
      tm = fmaxf(tm, __shfl_xor(tm, 16));
      tm = fmaxf(tm, __shfl_xor(tm, 32));
      if (!__all(tm - mx <= 8.0f)) {      // wave-uniform; rare after warm-up
        const float mnew = fmaxf(mx, tm);
        const float sc = exp2f(mx - mnew);
        L *= sc;
        float scr[4];
#pragma unroll
        for (int r = 0; r < 4; ++r)
          scr[r] = __shfl(sc, (lane & 48) | (g4 * 4 + r));
#pragma unroll
        for (int nf = 0; nf < 4; ++nf)
#pragma unroll
          for (int r = 0; r < 4; ++r) o[nf][r] *= scr[r];
        mx = mnew;
      }
      float rs = 0.f;
#pragma unroll
      for (int c = 0; c < 4; ++c)
#pragma unroll
        for (int r = 0; r < 4; ++r) {
          s[c][r] = exp2f(s[c][r] - mx);  // bounded by 2^8
          rs += s[c][r];
        }
      rs += __shfl_xor(rs, 16);
      rs += __shfl_xor(rs, 32);
      L += rs;

      // ---- P -> PV A-fragments, in-lane (kappa ordering) ----
      bf16x8 ap0, ap1;
#pragma unroll
      for (int r = 0; r < 4; ++r) {
        ap0[r]     = f2bf(s[0][r]);
        ap0[4 + r] = f2bf(s[1][r]);
        ap1[r]     = f2bf(s[2][r]);
        ap1[4 + r] = f2bf(s[3][r]);
      }

      // ---- PV: o[q][d] += P V, keys in kappa order on both operands ----
#pragma unroll
      for (int nf = 0; nf < 4; ++nf) {
        const int d  = nf * 16 + l15;
        const int h3 = (2 * nf + (l15 >> 3)) & 7;   // (d>>3)&7
        bf16x8 vf0 = *(const bf16x8*)&VtC[d * PLD + ((g4 ^ h3) << 3)];
        bf16x8 vf1 = *(const bf16x8*)&VtC[d * PLD + (((g4 + 4) ^ h3) << 3)];
        o[nf] = __builtin_amdgcn_mfma_f32_16x16x32_bf16(ap0, vf0, o[nf], 0, 0, 0);
        o[nf] = __builtin_amdgcn_mfma_f32_16x16x32_bf16(ap1, vf1, o[nf], 0, 0, 0);
      }
    }

    if (it + 1 < ntiles) {                // write prefetched tile into the other buffer
      bf16_t* KsN = Ks + (cur ^ 1) * KSB;
      bf16_t* VtN = Vt + (cur ^ 1) * VTB;
      *(uint4*)&KsN[skk * 64 + ksw] = kv;
      const bf16_t* vb = (const bf16_t*)&vv;
#pragma unroll
      for (int i = 0; i < 8; ++i)
        VtN[(sd0 + i) * PLD + pos] = vb[i];
    }
    __syncthreads();
  }

  const int bb = bh / H_, hh = bh % H_;
  float il[4];
#pragma unroll
  for (int r = 0; r < 4; ++r)
    il[r] = 1.0f / __shfl(L, (lane & 48) | (g4 * 4 + r));
#pragma unroll
  for (int nf = 0; nf < 4; ++nf)
#pragma unroll
    for (int r = 0; r < 4; ++r) {
      const int row = rowb + r;
      y[(size_t)(bb * T_ + row) * C_ + hh * D_ + nf * 16 + l15] = f2bf(o[nf][r] * il[r]);
    }
}

// ---------------- GEMM2: out = y @ w_proj + b_proj (fp32 out) ----------------
// 1D grid + XCD swizzle (256 = 8 XCD x 32; one n-tile per XCD)
__global__ __launch_bounds__(256) void proj_gemm(const bf16_t* __restrict__ yin,
                                                 const bf16_t* __restrict__ wT,
                                                 const float* __restrict__ bias,
                                                 float* __restrict__ out) {
  __shared__ __align__(16) bf16_t smem[4 * GTILE];
  f32x4 acc[4][4];
  const int bid = blockIdx.x;
  const int swz = (bid & 7) * 32 + (bid >> 3);
  const int m0 = (swz & 31) * 128, n0 = (swz >> 5) * 128;
  gemm_core(yin, wT, m0, n0, smem, acc);

  const int t = threadIdx.x;
  const int lane = t & 63, w = t >> 6;
  const int wr = (w >> 1) * 64, wc = (w & 1) * 64;
  const int l15 = lane & 15, g4 = lane >> 4;
  const int ng = n0 + wc;
#pragma unroll
  for (int mi = 0; mi < 4; ++mi) {
    const int rowb = m0 + wr + mi * 16 + g4 * 4;
#pragma unroll
    for (int ni = 0; ni < 4; ++ni) {
      const int n = ng + ni * 16 + l15;
      const float b1 = bias[n];
#pragma unroll
      for (int r = 0; r < 4; ++r)
        out[(size_t)(rowb + r) * C_ + n] = acc[mi][ni][r] + b1;
    }
  }
}

// ---------------- launch ----------------
extern "C" void kernel_launch(void* const* d_in, const int* in_sizes, int n_in,
                              void* d_out, int out_size, void* d_ws, size_t ws_size,
                              hipStream_t stream) {
  (void)in_sizes; (void)n_in; (void)out_size; (void)ws_size;
  const float* x      = (const float*)d_in[0];
  const float* w_attn = (const float*)d_in[1];
  const float* b_attn = (const float*)d_in[2];
  const float* w_proj = (const float*)d_in[3];
  const float* b_proj = (const float*)d_in[4];
  float* out = (float*)d_out;

  char* ws = (char*)d_ws;
  bf16_t* wTa = (bf16_t*)ws;  ws += (size_t)NQKV_ * C_ * 2;          // 6 MB
  bf16_t* wTp = (bf16_t*)ws;  ws += (size_t)C_ * C_ * 2;             // 2 MB
  bf16_t* qb  = (bf16_t*)ws;  ws += (size_t)B_ * H_ * T_ * D_ * 2;   // 8 MB
  bf16_t* kb  = (bf16_t*)ws;  ws += (size_t)B_ * H_ * T_ * D_ * 2;   // 8 MB
  bf16_t* vb  = (bf16_t*)ws;  ws += (size_t)B_ * H_ * T_ * D_ * 2;   // 8 MB
  bf16_t* yb  = (bf16_t*)ws;  ws += (size_t)B_ * T_ * C_ * 2;        // 8 MB
  float2* rtab = (float2*)ws; ws += (size_t)T_ * 32 * sizeof(float2);// 0.5 MB
  // x_bf aliases yb: x_bf is consumed by qkv_gemm (dispatch 2) strictly before
  // attn_fwd (dispatch 3) writes yb. Stream-ordered, deterministic.
  bf16_t* x_bf = yb;

  // fused prep: 256 rope + 3072 tA + 1024 tP + 2048 convert = 6400 blocks
  prep_k<<<dim3(6400), 256, 0, stream>>>(rtab, w_attn, wTa, w_proj, wTp, x, x_bf);
  qkv_gemm<<<dim3((M_ / 128) * (NQKV_ / 384)), 512, 0, stream>>>(x_bf, wTa, b_attn, rtab, qb, kb, vb);
  attn_fwd<<<dim3(NQT2 * 32), 512, 0, stream>>>(qb, kb, vb, yb);
  proj_gemm<<<dim3((M_ / 128) * (C_ / 128)), 256, 0, stream>>>(yb, wTp, b_proj, out);
}

// Round 24
// 101.361 us; speedup vs baseline: 1.1201x; 1.0295x over previous
//
#include <hip/hip_runtime.h>
#include <hip/hip_bf16.h>

typedef __bf16 bf16_t;
typedef __bf16 bf16x8 __attribute__((ext_vector_type(8)));
typedef float f32x4 __attribute__((ext_vector_type(4)));
typedef float f32x8v __attribute__((ext_vector_type(8)));

#define B_    2
#define T_    2048
#define C_    1024
#define H_    16
#define D_    64
#define M_    4096      // B*T
#define NQKV_ 3072
#define PLD   72        // attn V^T LDS row stride
#define NQT2  16        // T_/128 q-tiles (attn)
#define GTILE (128 * 64)   // proj GEMM LDS tile (elements)
#define SLOT2 32768        // qkv ring slot elements (A 128x64 + B 384x64)
#define KSB   4096         // attn Ks buffer elements (64x64)
#define VTB   (64 * PLD)   // attn Vt buffer elements

static __device__ __forceinline__ float  bf2f(bf16_t x) { return (float)x; }
static __device__ __forceinline__ bf16_t f2bf(float x)  { return (bf16_t)x; }

// async global->LDS, 16B per lane; LDS dest is wave-uniform base + lane*16 (HW rule)
typedef const __attribute__((address_space(1))) void gas_void;
typedef __attribute__((address_space(3))) void las_void;
static __device__ __forceinline__ void gld16(const void* g, void* l) {
  __builtin_amdgcn_global_load_lds((gas_void*)g, (las_void*)l, 16, 0, 0);
}

// ---- fused prep: rope table | w_attn transpose | w_proj transpose | x->bf16 ----
__global__ __launch_bounds__(256) void prep_k(float2* __restrict__ rtab,
                                              const float* __restrict__ w_attn,
                                              bf16_t* __restrict__ wTa,
                                              const float* __restrict__ w_proj,
                                              bf16_t* __restrict__ wTp,
                                              const float* __restrict__ x,
                                              bf16_t* __restrict__ x_bf) {
  __shared__ bf16_t tile[32][33];
  const int bid = blockIdx.x;

  if (bid < 256) {                       // rope table: [T][32] float2
    int i = bid * 256 + threadIdx.x;
    int tpos = i >> 5, d = i & 31;
    float fr = exp2f(-(float)d * (13.287712379549449f / 32.0f));
    float ang = (float)tpos * fr;
    rtab[i] = make_float2(cosf(ang), sinf(ang));
    return;
  }
  if (bid < 256 + 3072) {                // transpose w_attn (C_ x NQKV_) -> wTa
    const int id = bid - 256;
    const int c0 = (id % 96) * 32, r0 = (id / 96) * 32;
    const int tx = threadIdx.x & 31, ty = threadIdx.x >> 5;
#pragma unroll
    for (int j = 0; j < 4; ++j)
      tile[ty + j * 8][tx] = f2bf(w_attn[(size_t)(r0 + ty + j * 8) * NQKV_ + c0 + tx]);
    __syncthreads();
#pragma unroll
    for (int j = 0; j < 4; ++j)
      wTa[(size_t)(c0 + ty + j * 8) * C_ + r0 + tx] = tile[tx][ty + j * 8];
    return;
  }
  if (bid < 256 + 3072 + 1024) {         // transpose w_proj (C_ x C_) -> wTp
    const int id = bid - (256 + 3072);
    const int c0 = (id % 32) * 32, r0 = (id / 32) * 32;
    const int tx = threadIdx.x & 31, ty = threadIdx.x >> 5;
#pragma unroll
    for (int j = 0; j < 4; ++j)
      tile[ty + j * 8][tx] = f2bf(w_proj[(size_t)(r0 + ty + j * 8) * C_ + c0 + tx]);
    __syncthreads();
#pragma unroll
    for (int j = 0; j < 4; ++j)
      wTp[(size_t)(c0 + ty + j * 8) * C_ + r0 + tx] = tile[tx][ty + j * 8];
    return;
  }
  {                                      // x fp32 -> bf16 (2048 blocks)
    const int id = bid - (256 + 3072 + 1024);
    const int i = (id * 256 + threadIdx.x) * 8;
    f32x8v v = *(const f32x8v*)(x + i);
    bf16x8 h;
#pragma unroll
    for (int j = 0; j < 8; ++j) h[j] = f2bf(v[j]);
    *(bf16x8*)(x_bf + i) = h;
  }
}

// ------- proj GEMM core (r11-verified): 128x128, dbuf global_load_lds, 2-barrier ----
__device__ __forceinline__ void gemm_core(const bf16_t* __restrict__ A,
                                          const bf16_t* __restrict__ Bt,
                                          int m0, int n0,
                                          bf16_t* sm,
                                          f32x4 acc[4][4]) {
  const int t    = threadIdx.x;
  const int lane = t & 63, w = t >> 6;
  const int wr = (w >> 1) * 64, wc = (w & 1) * 64;
  const int l15 = lane & 15, g4 = lane >> 4;

  const f32x4 z4 = {0.f, 0.f, 0.f, 0.f};
#pragma unroll
  for (int i = 0; i < 4; ++i)
#pragma unroll
    for (int j = 0; j < 4; ++j) acc[i][j] = z4;

  const int srow = w * 32 + (lane >> 3);
  const int sel8 = (lane & 7) * 8;
  const bf16_t* gA = A  + (size_t)(m0 + srow) * C_ + sel8;
  const bf16_t* gB = Bt + (size_t)(n0 + srow) * C_ + sel8;
  const int dOff = (w * 32) * 64;

#pragma unroll
  for (int j = 0; j < 4; ++j) {
    gld16(gA + (size_t)(j * 8) * C_, sm + dOff + j * 8 * 64);
    gld16(gB + (size_t)(j * 8) * C_, sm + GTILE + dOff + j * 8 * 64);
  }
  __syncthreads();

  int cur = 0;
  for (int kt = 0; kt < C_ / 64; ++kt) {
    if (kt + 1 < C_ / 64) {
      const int k0 = (kt + 1) * 64;
      bf16_t* nA = sm + (cur ^ 1) * (2 * GTILE);
      bf16_t* nB = nA + GTILE;
#pragma unroll
      for (int j = 0; j < 4; ++j) {
        gld16(gA + (size_t)(j * 8) * C_ + k0, nA + dOff + j * 8 * 64);
        gld16(gB + (size_t)(j * 8) * C_ + k0, nB + dOff + j * 8 * 64);
      }
    }
    const bf16_t* lA = sm + cur * (2 * GTILE);
    const bf16_t* lB = lA + GTILE;
#pragma unroll
    for (int ks = 0; ks < 2; ++ks) {
      bf16x8 af[4], bfv[4];
#pragma unroll
      for (int mi = 0; mi < 4; ++mi)
        af[mi] = *(const bf16x8*)&lA[(wr + mi * 16 + l15) * 64 + ks * 32 + g4 * 8];
#pragma unroll
      for (int ni = 0; ni < 4; ++ni)
        bfv[ni] = *(const bf16x8*)&lB[(wc + ni * 16 + l15) * 64 + ks * 32 + g4 * 8];
#pragma unroll
      for (int mi = 0; mi < 4; ++mi)
#pragma unroll
        for (int ni = 0; ni < 4; ++ni)
          acc[mi][ni] = __builtin_amdgcn_mfma_f32_16x16x32_bf16(af[mi], bfv[ni],
                                                                acc[mi][ni], 0, 0, 0);
    }
    __syncthreads();
    cur ^= 1;
  }
}

// ---- GEMM1: qkv, 128x384 tile, BK=64 2-slot ring (r21-verified, full CU coverage) ----
__global__ __launch_bounds__(512, 2) void qkv_gemm(const bf16_t* __restrict__ x,
                                                   const bf16_t* __restrict__ wT,
                                                   const float* __restrict__ bias,
                                                   const float2* __restrict__ rtab,
                                                   bf16_t* __restrict__ qo,
                                                   bf16_t* __restrict__ ko,
                                                   bf16_t* __restrict__ vo) {
  __shared__ __align__(16) bf16_t sm[2 * SLOT2];       // 128 KB ring; reused as store stage
  const int t = threadIdx.x;
  const int lane = t & 63, w = t >> 6;                 // 8 waves
  const int l15 = lane & 15, g4 = lane >> 4;
  const int wr = (w >> 1) * 32, wc = (w & 1) * 192;    // 4M x 2N -> 32x192 per wave

  const int bid = blockIdx.x;                          // 256 = 32m x 8n tiles
  const int swz = (bid & 7) * 32 + (bid >> 3);         // XCD-chunked, n-major
  const int m0 = (swz & 31) * 128, n0 = (swz >> 5) * 384;

  const f32x4 z4 = {0.f, 0.f, 0.f, 0.f};
  f32x4 acc[2][12];
#pragma unroll
  for (int i = 0; i < 2; ++i)
#pragma unroll
    for (int j = 0; j < 12; ++j) acc[i][j] = z4;

  const int sr8 = lane >> 3;
  const int swc = ((lane & 7) ^ ((lane >> 3) & 7)) * 8;
  const bf16_t* gA = x  + (size_t)(m0 + w * 16 + sr8) * C_ + swc;
  const bf16_t* gB = wT + (size_t)(n0 + w * 48 + sr8) * C_ + swc;

#define QKV_STAGE(h)                                                            \
  {                                                                             \
    bf16_t* sl = sm + ((h) & 1) * SLOT2;                                        \
    const size_t kofs = (size_t)(h) * 64;                                       \
    gld16(gA + kofs,            sl + (w * 16 +  0) * 64);                       \
    gld16(gA +  8 * C_ + kofs,  sl + (w * 16 +  8) * 64);                       \
    gld16(gB + kofs,            sl + 8192 + (w * 48 +  0) * 64);                \
    gld16(gB +  8 * C_ + kofs,  sl + 8192 + (w * 48 +  8) * 64);                \
    gld16(gB + 16 * C_ + kofs,  sl + 8192 + (w * 48 + 16) * 64);                \
    gld16(gB + 24 * C_ + kofs,  sl + 8192 + (w * 48 + 24) * 64);                \
    gld16(gB + 32 * C_ + kofs,  sl + 8192 + (w * 48 + 32) * 64);                \
    gld16(gB + 40 * C_ + kofs,  sl + 8192 + (w * 48 + 40) * 64);                \
  }

  QKV_STAGE(0);

  const int csw = l15 & 7;                // read-side swizzle bits (= row&7)

  for (int h = 0; h < 16; ++h) {
    asm volatile("s_waitcnt vmcnt(0)" ::: "memory");
    __builtin_amdgcn_sched_barrier(0);
    __builtin_amdgcn_s_barrier();
    __builtin_amdgcn_sched_barrier(0);
    if (h + 1 < 16) QKV_STAGE(h + 1);     // slot freed by the barrier above

    const bf16_t* sl = sm + (h & 1) * SLOT2;
#pragma unroll
    for (int ks = 0; ks < 2; ++ks) {
      bf16x8 af[2], bfv[12];
#pragma unroll
      for (int mi = 0; mi < 2; ++mi)
        af[mi] = *(const bf16x8*)&sl[(wr + mi * 16 + l15) * 64 + (((ks * 4 + g4) ^ csw) * 8)];
#pragma unroll
      for (int ni = 0; ni < 12; ++ni)
        bfv[ni] = *(const bf16x8*)&sl[8192 + (wc + ni * 16 + l15) * 64 + (((ks * 4 + g4) ^ csw) * 8)];
#pragma unroll
      for (int mi = 0; mi < 2; ++mi)
#pragma unroll
        for (int ni = 0; ni < 12; ++ni)
          acc[mi][ni] = __builtin_amdgcn_mfma_f32_16x16x32_bf16(af[mi], bfv[ni],
                                                                acc[mi][ni], 0, 0, 0);
    }
  }
#undef QKV_STAGE

  __syncthreads();                       // all compute done; reuse sm as store stage
  bf16_t* stg = sm + w * 6144;           // per-wave 32x192 stage (96 KB total)

#pragma unroll
  for (int cc = 0; cc < 3; ++cc) {
    const int ngc = n0 + (w & 1) * 192 + cc * 64;   // 64-aligned chunk -> single (sel, head)
    const int sel = ngc >> 10;
    if (sel < 2) {
      const float qs = (sel == 0) ? 0.125f * 1.4426950408889634f : 1.0f;
#pragma unroll
      for (int mi = 0; mi < 2; ++mi) {
#pragma unroll
        for (int nq = 0; nq < 2; ++nq) {
          const int d1 = nq * 16 + l15;        // 0..31; partner is d1+32 (frag nq+2)
          const float b1 = bias[ngc + d1];
          const float b2 = bias[ngc + d1 + 32];
#pragma unroll
          for (int r = 0; r < 4; ++r) {
            const int lrow = mi * 16 + g4 * 4 + r;
            const int tpos = (m0 + wr + lrow) & (T_ - 1);
            const float2 cs = rtab[tpos * 32 + d1];
            const float x1 = acc[mi][cc * 4 + nq][r]     + b1;
            const float x2 = acc[mi][cc * 4 + nq + 2][r] + b2;
            stg[lrow * 192 + cc * 64 + d1]      = f2bf((x1 * cs.x - x2 * cs.y) * qs);
            stg[lrow * 192 + cc * 64 + d1 + 32] = f2bf((x1 * cs.y + x2 * cs.x) * qs);
          }
        }
      }
    } else {
#pragma unroll
      for (int mi = 0; mi < 2; ++mi)
#pragma unroll
        for (int nq = 0; nq < 4; ++nq) {
          const int d = nq * 16 + l15;
          const float b1 = bias[ngc + d];
#pragma unroll
          for (int r = 0; r < 4; ++r)
            stg[(mi * 16 + g4 * 4 + r) * 192 + cc * 64 + d] = f2bf(acc[mi][cc * 4 + nq][r] + b1);
        }
    }
  }

  // readback own region (intra-wave dep only) + 1KB-per-instruction stores
  const int a  = lane >> 3;        // row-in-group 0..7
  const int b8 = (lane & 7) * 8;   // col chunk (x8 bf16 = 16B)
#pragma unroll
  for (int cc = 0; cc < 3; ++cc) {
    const int ngc = n0 + (w & 1) * 192 + cc * 64;
    const int sel = ngc >> 10;
    const int hh  = (ngc & 1023) >> 6;
    bf16_t* outp = (sel == 0) ? qo : (sel == 1 ? ko : vo);
#pragma unroll
    for (int pp = 0; pp < 4; ++pp) {
      const int lrow = pp * 8 + a;
      const int row  = m0 + wr + lrow;
      const int tpos = row & (T_ - 1);
      const int bb   = row >> 11;
      uint4 val = *(const uint4*)&stg[lrow * 192 + cc * 64 + b8];
      *(uint4*)(outp + ((size_t)(bb * H_ + hh) * T_ + tpos) * D_ + b8) = val;
    }
  }
}

// ---- flash attention, swapped-QK: 128 q-rows (8 waves x 16), 128 keys per barrier ----
// r18 structure with TWO 64-key subtiles per barrier period: all per-64 index math
// (swizzles, kappa slots, mask via 64-tile index itt=2*it+sub, softmax sequence)
// byte-identical; only loop nesting + staging regs (2x uint4) + buffer count change.
// Barriers per key halved (r17 accounting: ~250-500cy lockstep edge per barrier).
__global__ __launch_bounds__(512) void attn_fwd(const bf16_t* __restrict__ q,
                                                const bf16_t* __restrict__ k,
                                                const bf16_t* __restrict__ v,
                                                bf16_t* __restrict__ y) {
  __shared__ __align__(16) bf16_t Ks[4 * KSB];         // [dbuf][sub] K rows, XOR-swizzled
  __shared__ __align__(16) bf16_t Vt[4 * VTB];         // [dbuf][sub] V^T kappa slots
  const int t = threadIdx.x;
  const int lane = t & 63, w = t >> 6;                 // w: 0..7
  const int l15 = lane & 15, g4 = lane >> 4;

  const int f   = blockIdx.x;
  const int idx = f & 255;
  const int bh  = idx & 31;
  const int p   = idx >> 5;                            // 0..7
  const int qt  = (f >> 8) ? (15 - p) : p;             // bijective over 0..15
  const int qb  = qt * 128;
  const size_t hb = (size_t)bh * T_ * D_;

  const int qrow = qb + w * 16 + l15;
  bf16x8 qf[2];
  qf[0] = *(const bf16x8*)(q + hb + (size_t)qrow * D_ + g4 * 8);
  qf[1] = *(const bf16x8*)(q + hb + (size_t)qrow * D_ + 32 + g4 * 8);

  const f32x4 z4 = {0.f, 0.f, 0.f, 0.f};
  f32x4 o[4];
#pragma unroll
  for (int i = 0; i < 4; ++i) o[i] = z4;
  float mx = -1e30f, L = 0.f;

  const int skk = t >> 3;                  // key row 0..63 within a subtile
  const int sd0 = (t & 7) * 8;
  const int u   = t & 7;                   // = (d>>3)&7 for all this thread's d rows
  const int ksw = sd0 ^ ((skk & 7) * 8);   // Ks swizzled col
  // kappa slot for key=skk: slot = 32*c1 + 8*g + 4*c0 + r
  const int slot = ((skk >> 5) & 1) * 32 + ((skk >> 2) & 3) * 8 + ((skk >> 4) & 1) * 4 + (skk & 3);
  const int pos  = (((slot >> 3) ^ u) << 3) | (slot & 7);
  const int rowb = qb + w * 16 + g4 * 4;

  const int ntp = qt + 1;                  // 128-key periods; 2*ntp 64-tiles total

  // prologue: stage period 0 (both subtiles) into dbuf 0
  {
    uint4 kv0 = *(const uint4*)(k + hb + (size_t)skk * D_ + sd0);
    uint4 kv1 = *(const uint4*)(k + hb + (size_t)(64 + skk) * D_ + sd0);
    uint4 vv0 = *(const uint4*)(v + hb + (size_t)skk * D_ + sd0);
    uint4 vv1 = *(const uint4*)(v + hb + (size_t)(64 + skk) * D_ + sd0);
    *(uint4*)&Ks[0 * KSB + skk * 64 + ksw] = kv0;
    *(uint4*)&Ks[1 * KSB + skk * 64 + ksw] = kv1;
    const bf16_t* vb0 = (const bf16_t*)&vv0;
    const bf16_t* vb1 = (const bf16_t*)&vv1;
#pragma unroll
    for (int i = 0; i < 8; ++i) {
      Vt[0 * VTB + (sd0 + i) * PLD + pos] = vb0[i];
      Vt[1 * VTB + (sd0 + i) * PLD + pos] = vb1[i];
    }
  }
  __syncthreads();

  uint4 kv0, kv1, vv0, vv1;
  for (int it = 0; it < ntp; ++it) {
    const int cur = it & 1;

    if (it + 1 < ntp) {                   // issue next period's loads (hide under compute)
      const size_t nb = hb + (size_t)((it + 1) * 128 + skk) * D_ + sd0;
      kv0 = *(const uint4*)(k + nb);
      kv1 = *(const uint4*)(k + nb + (size_t)64 * D_);
      vv0 = *(const uint4*)(v + nb);
      vv1 = *(const uint4*)(v + nb + (size_t)64 * D_);
    }

#pragma unroll
    for (int sub = 0; sub < 2; ++sub) {
      const int itt = 2 * it + sub;       // 64-tile index (matches r18 semantics)
      const int kb  = itt * 64;
      const bool last = (itt == 2 * ntp - 1);
      const bool pen  = (itt == 2 * ntp - 2);
      if (last && w < 4) continue;        // fully-masked subtile: skip compute only

      const bf16_t* KsC = Ks + (cur * 2 + sub) * KSB;
      const bf16_t* VtC = Vt + (cur * 2 + sub) * VTB;

      // ---- QK^T swapped: s[c][r] = S[key=kb+c*16+g4*4+r][q=qrow] ----
      f32x4 s[4];
#pragma unroll
      for (int c = 0; c < 4; ++c) s[c] = z4;
#pragma unroll
      for (int ks = 0; ks < 2; ++ks)
#pragma unroll
        for (int c = 0; c < 4; ++c) {
          const int kr = c * 16 + l15;
          bf16x8 kf = *(const bf16x8*)&KsC[kr * 64 + ((ks * 32 + g4 * 8) ^ ((kr & 7) * 8))];
          s[c] = __builtin_amdgcn_mfma_f32_16x16x32_bf16(kf, qf[ks], s[c], 0, 0, 0);
        }

      // ---- causal mask: only the two diagonal-adjacent 64-tiles can violate ----
      if (last || (pen && w < 4)) {
#pragma unroll
        for (int c = 0; c < 4; ++c)
#pragma unroll
          for (int r = 0; r < 4; ++r)
            if (kb + c * 16 + g4 * 4 + r > qrow) s[c][r] = -1e30f;
      }

      // ---- online softmax (exp2 domain; defer-max THR=8) ----
      float tm = -1e30f;
#pragma unroll
      for (int c = 0; c < 4; ++c)
#pragma unroll
        for (int r = 0; r < 4; ++r) tm = fmaxf(tm, s[c][r]);
      tm = fmaxf(tm, __shfl_xor(tm, 16));
      tm = fmaxf(tm, __shfl_xor(tm, 32));
      if (!__all(tm - mx <= 8.0f)) {      // wave-uniform; rare after warm-up
        const float mnew = fmaxf(mx, tm);
        const float sc = exp2f(mx - mnew);
        L *= sc;
        float scr[4];
#pragma unroll
        for (int r = 0; r < 4; ++r)
          scr[r] = __shfl(sc, (lane & 48) | (g4 * 4 + r));
#pragma unroll
        for (int nf = 0; nf < 4; ++nf)
#pragma unroll
          for (int r = 0; r < 4; ++r) o[nf][r] *= scr[r];
        mx = mnew;
      }
      float rs = 0.f;
#pragma unroll
      for (int c = 0; c < 4; ++c)
#pragma unroll
        for (int r = 0; r < 4; ++r) {
          s[c][r] = exp2f(s[c][r] - mx);  // bounded by 2^8
          rs += s[c][r];
        }
      rs += __shfl_xor(rs, 16);
      rs += __shfl_xor(rs, 32);
      L += rs;

      // ---- P -> PV A-fragments, in-lane (kappa ordering) ----
      bf16x8 ap0, ap1;
#pragma unroll
      for (int r = 0; r < 4; ++r) {
        ap0[r]     = f2bf(s[0][r]);
        ap0[4 + r] = f2bf(s[1][r]);
        ap1[r]     = f2bf(s[2][r]);
        ap1[4 + r] = f2bf(s[3][r]);
      }

      // ---- PV: o[q][d] += P V, keys in kappa order on both operands ----
#pragma unroll
      for (int nf = 0; nf < 4; ++nf) {
        const int d  = nf * 16 + l15;
        const int h3 = (2 * nf + (l15 >> 3)) & 7;   // (d>>3)&7
        bf16x8 vf0 = *(const bf16x8*)&VtC[d * PLD + ((g4 ^ h3) << 3)];
        bf16x8 vf1 = *(const bf16x8*)&VtC[d * PLD + (((g4 + 4) ^ h3) << 3)];
        o[nf] = __builtin_amdgcn_mfma_f32_16x16x32_bf16(ap0, vf0, o[nf], 0, 0, 0);
        o[nf] = __builtin_amdgcn_mfma_f32_16x16x32_bf16(ap1, vf1, o[nf], 0, 0, 0);
      }
    }

    if (it + 1 < ntp) {                   // write prefetched period into the other dbuf
      bf16_t* Ks0 = Ks + ((cur ^ 1) * 2 + 0) * KSB;
      bf16_t* Ks1 = Ks + ((cur ^ 1) * 2 + 1) * KSB;
      bf16_t* Vt0 = Vt + ((cur ^ 1) * 2 + 0) * VTB;
      bf16_t* Vt1 = Vt + ((cur ^ 1) * 2 + 1) * VTB;
      *(uint4*)&Ks0[skk * 64 + ksw] = kv0;
      *(uint4*)&Ks1[skk * 64 + ksw] = kv1;
      const bf16_t* vb0 = (const bf16_t*)&vv0;
      const bf16_t* vb1 = (const bf16_t*)&vv1;
#pragma unroll
      for (int i = 0; i < 8; ++i) {
        Vt0[(sd0 + i) * PLD + pos] = vb0[i];
        Vt1[(sd0 + i) * PLD + pos] = vb1[i];
      }
    }
    __syncthreads();
  }

  const int bb = bh / H_, hh = bh % H_;
  float il[4];
#pragma unroll
  for (int r = 0; r < 4; ++r)
    il[r] = 1.0f / __shfl(L, (lane & 48) | (g4 * 4 + r));
#pragma unroll
  for (int nf = 0; nf < 4; ++nf)
#pragma unroll
    for (int r = 0; r < 4; ++r) {
      const int row = rowb + r;
      y[(size_t)(bb * T_ + row) * C_ + hh * D_ + nf * 16 + l15] = f2bf(o[nf][r] * il[r]);
    }
}

// ---------------- GEMM2: out = y @ w_proj + b_proj (fp32 out) ----------------
// 1D grid + XCD swizzle (256 = 8 XCD x 32; one n-tile per XCD)
__global__ __launch_bounds__(256) void proj_gemm(const bf16_t* __restrict__ yin,
                                                 const bf16_t* __restrict__ wT,
                                                 const float* __restrict__ bias,
                                                 float* __restrict__ out) {
  __shared__ __align__(16) bf16_t smem[4 * GTILE];
  f32x4 acc[4][4];
  const int bid = blockIdx.x;
  const int swz = (bid & 7) * 32 + (bid >> 3);
  const int m0 = (swz & 31) * 128, n0 = (swz >> 5) * 128;
  gemm_core(yin, wT, m0, n0, smem, acc);

  const int t = threadIdx.x;
  const int lane = t & 63, w = t >> 6;
  const int wr = (w >> 1) * 64, wc = (w & 1) * 64;
  const int l15 = lane & 15, g4 = lane >> 4;
  const int ng = n0 + wc;
#pragma unroll
  for (int mi = 0; mi < 4; ++mi) {
    const int rowb = m0 + wr + mi * 16 + g4 * 4;
#pragma unroll
    for (int ni = 0; ni < 4; ++ni) {
      const int n = ng + ni * 16 + l15;
      const float b1 = bias[n];
#pragma unroll
      for (int r = 0; r < 4; ++r)
        out[(size_t)(rowb + r) * C_ + n] = acc[mi][ni][r] + b1;
    }
  }
}

// ---------------- launch ----------------
extern "C" void kernel_launch(void* const* d_in, const int* in_sizes, int n_in,
                              void* d_out, int out_size, void* d_ws, size_t ws_size,
                              hipStream_t stream) {
  (void)in_sizes; (void)n_in; (void)out_size; (void)ws_size;
  const float* x      = (const float*)d_in[0];
  const float* w_attn = (const float*)d_in[1];
  const float* b_attn = (const float*)d_in[2];
  const float* w_proj = (const float*)d_in[3];
  const float* b_proj = (const float*)d_in[4];
  float* out = (float*)d_out;

  char* ws = (char*)d_ws;
  bf16_t* wTa = (bf16_t*)ws;  ws += (size_t)NQKV_ * C_ * 2;          // 6 MB
  bf16_t* wTp = (bf16_t*)ws;  ws += (size_t)C_ * C_ * 2;             // 2 MB
  bf16_t* qb  = (bf16_t*)ws;  ws += (size_t)B_ * H_ * T_ * D_ * 2;   // 8 MB
  bf16_t* kb  = (bf16_t*)ws;  ws += (size_t)B_ * H_ * T_ * D_ * 2;   // 8 MB
  bf16_t* vb  = (bf16_t*)ws;  ws += (size_t)B_ * H_ * T_ * D_ * 2;   // 8 MB
  bf16_t* yb  = (bf16_t*)ws;  ws += (size_t)B_ * T_ * C_ * 2;        // 8 MB
  float2* rtab = (float2*)ws; ws += (size_t)T_ * 32 * sizeof(float2);// 0.5 MB
  // x_bf aliases yb: x_bf is consumed by qkv_gemm (dispatch 2) strictly before
  // attn_fwd (dispatch 3) writes yb. Stream-ordered, deterministic.
  bf16_t* x_bf = yb;

  // fused prep: 256 rope + 3072 tA + 1024 tP + 2048 convert = 6400 blocks
  prep_k<<<dim3(6400), 256, 0, stream>>>(rtab, w_attn, wTa, w_proj, wTp, x, x_bf);
  qkv_gemm<<<dim3((M_ / 128) * (NQKV_ / 384)), 512, 0, stream>>>(x_bf, wTa, b_attn, rtab, qb, kb, vb);
  attn_fwd<<<dim3(NQT2 * 32), 512, 0, stream>>>(qb, kb, vb, yb);
  proj_gemm<<<dim3((M_ / 128) * (C_ / 128)), 256, 0, stream>>>(yb, wTp, b_proj, out);
}

// Round 25
// 99.640 us; speedup vs baseline: 1.1394x; 1.0173x over previous
//
#include <hip/hip_runtime.h>
#include <hip/hip_bf16.h>

typedef __bf16 bf16_t;
typedef __bf16 bf16x8 __attribute__((ext_vector_type(8)));
typedef float f32x4 __attribute__((ext_vector_type(4)));
typedef float f32x8v __attribute__((ext_vector_type(8)));

#define B_    2
#define T_    2048
#define C_    1024
#define H_    16
#define D_    64
#define M_    4096      // B*T
#define NQKV_ 3072
#define PLD   72        // attn V^T LDS row stride
#define NQT2  16        // T_/128 q-tiles (attn)
#define GTILE (128 * 64)   // proj GEMM LDS tile (elements)
#define SLOT2 32768        // qkv ring slot elements (A 128x64 + B 384x64)
#define KSB   4096         // attn Ks buffer elements (64x64)
#define VTB   (64 * PLD)   // attn Vt buffer elements

static __device__ __forceinline__ float  bf2f(bf16_t x) { return (float)x; }
static __device__ __forceinline__ bf16_t f2bf(float x)  { return (bf16_t)x; }

// async global->LDS, 16B per lane; LDS dest is wave-uniform base + lane*16 (HW rule)
typedef const __attribute__((address_space(1))) void gas_void;
typedef __attribute__((address_space(3))) void las_void;
static __device__ __forceinline__ void gld16(const void* g, void* l) {
  __builtin_amdgcn_global_load_lds((gas_void*)g, (las_void*)l, 16, 0, 0);
}

// ---- fused prep: rope table | w_attn transpose | w_proj transpose | x->bf16 ----
__global__ __launch_bounds__(256) void prep_k(float2* __restrict__ rtab,
                                              const float* __restrict__ w_attn,
                                              bf16_t* __restrict__ wTa,
                                              const float* __restrict__ w_proj,
                                              bf16_t* __restrict__ wTp,
                                              const float* __restrict__ x,
                                              bf16_t* __restrict__ x_bf) {
  __shared__ bf16_t tile[32][33];
  const int bid = blockIdx.x;

  if (bid < 256) {                       // rope table: [T][32] float2
    int i = bid * 256 + threadIdx.x;
    int tpos = i >> 5, d = i & 31;
    float fr = exp2f(-(float)d * (13.287712379549449f / 32.0f));
    float ang = (float)tpos * fr;
    rtab[i] = make_float2(cosf(ang), sinf(ang));
    return;
  }
  if (bid < 256 + 3072) {                // transpose w_attn (C_ x NQKV_) -> wTa
    const int id = bid - 256;
    const int c0 = (id % 96) * 32, r0 = (id / 96) * 32;
    const int tx = threadIdx.x & 31, ty = threadIdx.x >> 5;
#pragma unroll
    for (int j = 0; j < 4; ++j)
      tile[ty + j * 8][tx] = f2bf(w_attn[(size_t)(r0 + ty + j * 8) * NQKV_ + c0 + tx]);
    __syncthreads();
#pragma unroll
    for (int j = 0; j < 4; ++j)
      wTa[(size_t)(c0 + ty + j * 8) * C_ + r0 + tx] = tile[tx][ty + j * 8];
    return;
  }
  if (bid < 256 + 3072 + 1024) {         // transpose w_proj (C_ x C_) -> wTp
    const int id = bid - (256 + 3072);
    const int c0 = (id % 32) * 32, r0 = (id / 32) * 32;
    const int tx = threadIdx.x & 31, ty = threadIdx.x >> 5;
#pragma unroll
    for (int j = 0; j < 4; ++j)
      tile[ty + j * 8][tx] = f2bf(w_proj[(size_t)(r0 + ty + j * 8) * C_ + c0 + tx]);
    __syncthreads();
#pragma unroll
    for (int j = 0; j < 4; ++j)
      wTp[(size_t)(c0 + ty + j * 8) * C_ + r0 + tx] = tile[tx][ty + j * 8];
    return;
  }
  {                                      // x fp32 -> bf16 (2048 blocks)
    const int id = bid - (256 + 3072 + 1024);
    const int i = (id * 256 + threadIdx.x) * 8;
    f32x8v v = *(const f32x8v*)(x + i);
    bf16x8 h;
#pragma unroll
    for (int j = 0; j < 8; ++j) h[j] = f2bf(v[j]);
    *(bf16x8*)(x_bf + i) = h;
  }
}

// ------- proj GEMM core (r11-verified): 128x128, dbuf global_load_lds, 2-barrier ----
__device__ __forceinline__ void gemm_core(const bf16_t* __restrict__ A,
                                          const bf16_t* __restrict__ Bt,
                                          int m0, int n0,
                                          bf16_t* sm,
                                          f32x4 acc[4][4]) {
  const int t    = threadIdx.x;
  const int lane = t & 63, w = t >> 6;
  const int wr = (w >> 1) * 64, wc = (w & 1) * 64;
  const int l15 = lane & 15, g4 = lane >> 4;

  const f32x4 z4 = {0.f, 0.f, 0.f, 0.f};
#pragma unroll
  for (int i = 0; i < 4; ++i)
#pragma unroll
    for (int j = 0; j < 4; ++j) acc[i][j] = z4;

  const int srow = w * 32 + (lane >> 3);
  const int sel8 = (lane & 7) * 8;
  const bf16_t* gA = A  + (size_t)(m0 + srow) * C_ + sel8;
  const bf16_t* gB = Bt + (size_t)(n0 + srow) * C_ + sel8;
  const int dOff = (w * 32) * 64;

#pragma unroll
  for (int j = 0; j < 4; ++j) {
    gld16(gA + (size_t)(j * 8) * C_, sm + dOff + j * 8 * 64);
    gld16(gB + (size_t)(j * 8) * C_, sm + GTILE + dOff + j * 8 * 64);
  }
  __syncthreads();

  int cur = 0;
  for (int kt = 0; kt < C_ / 64; ++kt) {
    if (kt + 1 < C_ / 64) {
      const int k0 = (kt + 1) * 64;
      bf16_t* nA = sm + (cur ^ 1) * (2 * GTILE);
      bf16_t* nB = nA + GTILE;
#pragma unroll
      for (int j = 0; j < 4; ++j) {
        gld16(gA + (size_t)(j * 8) * C_ + k0, nA + dOff + j * 8 * 64);
        gld16(gB + (size_t)(j * 8) * C_ + k0, nB + dOff + j * 8 * 64);
      }
    }
    const bf16_t* lA = sm + cur * (2 * GTILE);
    const bf16_t* lB = lA + GTILE;
#pragma unroll
    for (int ks = 0; ks < 2; ++ks) {
      bf16x8 af[4], bfv[4];
#pragma unroll
      for (int mi = 0; mi < 4; ++mi)
        af[mi] = *(const bf16x8*)&lA[(wr + mi * 16 + l15) * 64 + ks * 32 + g4 * 8];
#pragma unroll
      for (int ni = 0; ni < 4; ++ni)
        bfv[ni] = *(const bf16x8*)&lB[(wc + ni * 16 + l15) * 64 + ks * 32 + g4 * 8];
#pragma unroll
      for (int mi = 0; mi < 4; ++mi)
#pragma unroll
        for (int ni = 0; ni < 4; ++ni)
          acc[mi][ni] = __builtin_amdgcn_mfma_f32_16x16x32_bf16(af[mi], bfv[ni],
                                                                acc[mi][ni], 0, 0, 0);
    }
    __syncthreads();
    cur ^= 1;
  }
}

// ---- GEMM1: qkv, 128x384 tile, BK=64 2-slot ring (r21-verified, full CU coverage) ----
__global__ __launch_bounds__(512, 2) void qkv_gemm(const bf16_t* __restrict__ x,
                                                   const bf16_t* __restrict__ wT,
                                                   const float* __restrict__ bias,
                                                   const float2* __restrict__ rtab,
                                                   bf16_t* __restrict__ qo,
                                                   bf16_t* __restrict__ ko,
                                                   bf16_t* __restrict__ vo) {
  __shared__ __align__(16) bf16_t sm[2 * SLOT2];       // 128 KB ring; reused as store stage
  const int t = threadIdx.x;
  const int lane = t & 63, w = t >> 6;                 // 8 waves
  const int l15 = lane & 15, g4 = lane >> 4;
  const int wr = (w >> 1) * 32, wc = (w & 1) * 192;    // 4M x 2N -> 32x192 per wave

  const int bid = blockIdx.x;                          // 256 = 32m x 8n tiles
  const int swz = (bid & 7) * 32 + (bid >> 3);         // XCD-chunked, n-major
  const int m0 = (swz & 31) * 128, n0 = (swz >> 5) * 384;

  const f32x4 z4 = {0.f, 0.f, 0.f, 0.f};
  f32x4 acc[2][12];
#pragma unroll
  for (int i = 0; i < 2; ++i)
#pragma unroll
    for (int j = 0; j < 12; ++j) acc[i][j] = z4;

  const int sr8 = lane >> 3;
  const int swc = ((lane & 7) ^ ((lane >> 3) & 7)) * 8;
  const bf16_t* gA = x  + (size_t)(m0 + w * 16 + sr8) * C_ + swc;
  const bf16_t* gB = wT + (size_t)(n0 + w * 48 + sr8) * C_ + swc;

#define QKV_STAGE(h)                                                            \
  {                                                                             \
    bf16_t* sl = sm + ((h) & 1) * SLOT2;                                        \
    const size_t kofs = (size_t)(h) * 64;                                       \
    gld16(gA + kofs,            sl + (w * 16 +  0) * 64);                       \
    gld16(gA +  8 * C_ + kofs,  sl + (w * 16 +  8) * 64);                       \
    gld16(gB + kofs,            sl + 8192 + (w * 48 +  0) * 64);                \
    gld16(gB +  8 * C_ + kofs,  sl + 8192 + (w * 48 +  8) * 64);                \
    gld16(gB + 16 * C_ + kofs,  sl + 8192 + (w * 48 + 16) * 64);                \
    gld16(gB + 24 * C_ + kofs,  sl + 8192 + (w * 48 + 24) * 64);                \
    gld16(gB + 32 * C_ + kofs,  sl + 8192 + (w * 48 + 32) * 64);                \
    gld16(gB + 40 * C_ + kofs,  sl + 8192 + (w * 48 + 40) * 64);                \
  }

  QKV_STAGE(0);

  const int csw = l15 & 7;                // read-side swizzle bits (= row&7)

  for (int h = 0; h < 16; ++h) {
    asm volatile("s_waitcnt vmcnt(0)" ::: "memory");
    __builtin_amdgcn_sched_barrier(0);
    __builtin_amdgcn_s_barrier();
    __builtin_amdgcn_sched_barrier(0);
    if (h + 1 < 16) QKV_STAGE(h + 1);     // slot freed by the barrier above

    const bf16_t* sl = sm + (h & 1) * SLOT2;
#pragma unroll
    for (int ks = 0; ks < 2; ++ks) {
      bf16x8 af[2], bfv[12];
#pragma unroll
      for (int mi = 0; mi < 2; ++mi)
        af[mi] = *(const bf16x8*)&sl[(wr + mi * 16 + l15) * 64 + (((ks * 4 + g4) ^ csw) * 8)];
#pragma unroll
      for (int ni = 0; ni < 12; ++ni)
        bfv[ni] = *(const bf16x8*)&sl[8192 + (wc + ni * 16 + l15) * 64 + (((ks * 4 + g4) ^ csw) * 8)];
#pragma unroll
      for (int mi = 0; mi < 2; ++mi)
#pragma unroll
        for (int ni = 0; ni < 12; ++ni)
          acc[mi][ni] = __builtin_amdgcn_mfma_f32_16x16x32_bf16(af[mi], bfv[ni],
                                                                acc[mi][ni], 0, 0, 0);
    }
  }
#undef QKV_STAGE

  __syncthreads();                       // all compute done; reuse sm as store stage
  bf16_t* stg = sm + w * 6144;           // per-wave 32x192 stage (96 KB total)

#pragma unroll
  for (int cc = 0; cc < 3; ++cc) {
    const int ngc = n0 + (w & 1) * 192 + cc * 64;   // 64-aligned chunk -> single (sel, head)
    const int sel = ngc >> 10;
    if (sel < 2) {
      const float qs = (sel == 0) ? 0.125f * 1.4426950408889634f : 1.0f;
#pragma unroll
      for (int mi = 0; mi < 2; ++mi) {
#pragma unroll
        for (int nq = 0; nq < 2; ++nq) {
          const int d1 = nq * 16 + l15;        // 0..31; partner is d1+32 (frag nq+2)
          const float b1 = bias[ngc + d1];
          const float b2 = bias[ngc + d1 + 32];
#pragma unroll
          for (int r = 0; r < 4; ++r) {
            const int lrow = mi * 16 + g4 * 4 + r;
            const int tpos = (m0 + wr + lrow) & (T_ - 1);
            const float2 cs = rtab[tpos * 32 + d1];
            const float x1 = acc[mi][cc * 4 + nq][r]     + b1;
            const float x2 = acc[mi][cc * 4 + nq + 2][r] + b2;
            stg[lrow * 192 + cc * 64 + d1]      = f2bf((x1 * cs.x - x2 * cs.y) * qs);
            stg[lrow * 192 + cc * 64 + d1 + 32] = f2bf((x1 * cs.y + x2 * cs.x) * qs);
          }
        }
      }
    } else {
#pragma unroll
      for (int mi = 0; mi < 2; ++mi)
#pragma unroll
        for (int nq = 0; nq < 4; ++nq) {
          const int d = nq * 16 + l15;
          const float b1 = bias[ngc + d];
#pragma unroll
          for (int r = 0; r < 4; ++r)
            stg[(mi * 16 + g4 * 4 + r) * 192 + cc * 64 + d] = f2bf(acc[mi][cc * 4 + nq][r] + b1);
        }
    }
  }

  // readback own region (intra-wave dep only) + 1KB-per-instruction stores
  const int a  = lane >> 3;        // row-in-group 0..7
  const int b8 = (lane & 7) * 8;   // col chunk (x8 bf16 = 16B)
#pragma unroll
  for (int cc = 0; cc < 3; ++cc) {
    const int ngc = n0 + (w & 1) * 192 + cc * 64;
    const int sel = ngc >> 10;
    const int hh  = (ngc & 1023) >> 6;
    bf16_t* outp = (sel == 0) ? qo : (sel == 1 ? ko : vo);
#pragma unroll
    for (int pp = 0; pp < 4; ++pp) {
      const int lrow = pp * 8 + a;
      const int row  = m0 + wr + lrow;
      const int tpos = row & (T_ - 1);
      const int bb   = row >> 11;
      uint4 val = *(const uint4*)&stg[lrow * 192 + cc * 64 + b8];
      *(uint4*)(outp + ((size_t)(bb * H_ + hh) * T_ + tpos) * D_ + b8) = val;
    }
  }
}

// ---- flash attention, swapped-QK: 128 q-rows (8 waves x 16), 128 keys per barrier ----
// r24 structure + L-on-MFMA: row-sum L computed as P x ones via 2 extra PV MFMAs into
// a 5th accumulator (any B-fragment of the all-ones matrix is all-ones -> layout-free).
// Removes per-subtile 16 VALU adds + 2 shfl (rs reduce) + final L shuffle; L now sums
// the same bf16-quantized P that PV consumes (sum-order delta << threshold).
__global__ __launch_bounds__(512) void attn_fwd(const bf16_t* __restrict__ q,
                                                const bf16_t* __restrict__ k,
                                                const bf16_t* __restrict__ v,
                                                bf16_t* __restrict__ y) {
  __shared__ __align__(16) bf16_t Ks[4 * KSB];         // [dbuf][sub] K rows, XOR-swizzled
  __shared__ __align__(16) bf16_t Vt[4 * VTB];         // [dbuf][sub] V^T kappa slots
  const int t = threadIdx.x;
  const int lane = t & 63, w = t >> 6;                 // w: 0..7
  const int l15 = lane & 15, g4 = lane >> 4;

  const int f   = blockIdx.x;
  const int idx = f & 255;
  const int bh  = idx & 31;
  const int p   = idx >> 5;                            // 0..7
  const int qt  = (f >> 8) ? (15 - p) : p;             // bijective over 0..15
  const int qb  = qt * 128;
  const size_t hb = (size_t)bh * T_ * D_;

  const int qrow = qb + w * 16 + l15;
  bf16x8 qf[2];
  qf[0] = *(const bf16x8*)(q + hb + (size_t)qrow * D_ + g4 * 8);
  qf[1] = *(const bf16x8*)(q + hb + (size_t)qrow * D_ + 32 + g4 * 8);

  const f32x4 z4 = {0.f, 0.f, 0.f, 0.f};
  f32x4 o[4];
#pragma unroll
  for (int i = 0; i < 4; ++i) o[i] = z4;
  f32x4 osum = z4;                         // L accumulator (P x ones), per q-row r
  float mx = -1e30f;
  bf16x8 ones8;
#pragma unroll
  for (int i = 0; i < 8; ++i) ones8[i] = f2bf(1.0f);

  const int skk = t >> 3;                  // key row 0..63 within a subtile
  const int sd0 = (t & 7) * 8;
  const int u   = t & 7;                   // = (d>>3)&7 for all this thread's d rows
  const int ksw = sd0 ^ ((skk & 7) * 8);   // Ks swizzled col
  // kappa slot for key=skk: slot = 32*c1 + 8*g + 4*c0 + r
  const int slot = ((skk >> 5) & 1) * 32 + ((skk >> 2) & 3) * 8 + ((skk >> 4) & 1) * 4 + (skk & 3);
  const int pos  = (((slot >> 3) ^ u) << 3) | (slot & 7);
  const int rowb = qb + w * 16 + g4 * 4;

  const int ntp = qt + 1;                  // 128-key periods; 2*ntp 64-tiles total

  // prologue: stage period 0 (both subtiles) into dbuf 0
  {
    uint4 kv0 = *(const uint4*)(k + hb + (size_t)skk * D_ + sd0);
    uint4 kv1 = *(const uint4*)(k + hb + (size_t)(64 + skk) * D_ + sd0);
    uint4 vv0 = *(const uint4*)(v + hb + (size_t)skk * D_ + sd0);
    uint4 vv1 = *(const uint4*)(v + hb + (size_t)(64 + skk) * D_ + sd0);
    *(uint4*)&Ks[0 * KSB + skk * 64 + ksw] = kv0;
    *(uint4*)&Ks[1 * KSB + skk * 64 + ksw] = kv1;
    const bf16_t* vb0 = (const bf16_t*)&vv0;
    const bf16_t* vb1 = (const bf16_t*)&vv1;
#pragma unroll
    for (int i = 0; i < 8; ++i) {
      Vt[0 * VTB + (sd0 + i) * PLD + pos] = vb0[i];
      Vt[1 * VTB + (sd0 + i) * PLD + pos] = vb1[i];
    }
  }
  __syncthreads();

  uint4 kv0, kv1, vv0, vv1;
  for (int it = 0; it < ntp; ++it) {
    const int cur = it & 1;

    if (it + 1 < ntp) {                   // issue next period's loads (hide under compute)
      const size_t nb = hb + (size_t)((it + 1) * 128 + skk) * D_ + sd0;
      kv0 = *(const uint4*)(k + nb);
      kv1 = *(const uint4*)(k + nb + (size_t)64 * D_);
      vv0 = *(const uint4*)(v + nb);
      vv1 = *(const uint4*)(v + nb + (size_t)64 * D_);
    }

#pragma unroll
    for (int sub = 0; sub < 2; ++sub) {
      const int itt = 2 * it + sub;       // 64-tile index (matches r18 semantics)
      const int kb  = itt * 64;
      const bool last = (itt == 2 * ntp - 1);
      const bool pen  = (itt == 2 * ntp - 2);
      if (last && w < 4) continue;        // fully-masked subtile: skip compute only

      const bf16_t* KsC = Ks + (cur * 2 + sub) * KSB;
      const bf16_t* VtC = Vt + (cur * 2 + sub) * VTB;

      // ---- QK^T swapped: s[c][r] = S[key=kb+c*16+g4*4+r][q=qrow] ----
      f32x4 s[4];
#pragma unroll
      for (int c = 0; c < 4; ++c) s[c] = z4;
#pragma unroll
      for (int ks = 0; ks < 2; ++ks)
#pragma unroll
        for (int c = 0; c < 4; ++c) {
          const int kr = c * 16 + l15;
          bf16x8 kf = *(const bf16x8*)&KsC[kr * 64 + ((ks * 32 + g4 * 8) ^ ((kr & 7) * 8))];
          s[c] = __builtin_amdgcn_mfma_f32_16x16x32_bf16(kf, qf[ks], s[c], 0, 0, 0);
        }

      // ---- causal mask: only the two diagonal-adjacent 64-tiles can violate ----
      if (last || (pen && w < 4)) {
#pragma unroll
        for (int c = 0; c < 4; ++c)
#pragma unroll
          for (int r = 0; r < 4; ++r)
            if (kb + c * 16 + g4 * 4 + r > qrow) s[c][r] = -1e30f;
      }

      // ---- online softmax (exp2 domain; defer-max THR=8; L on MFMA) ----
      float tm = -1e30f;
#pragma unroll
      for (int c = 0; c < 4; ++c)
#pragma unroll
        for (int r = 0; r < 4; ++r) tm = fmaxf(tm, s[c][r]);
      tm = fmaxf(tm, __shfl_xor(tm, 16));
      tm = fmaxf(tm, __shfl_xor(tm, 32));
      if (!__all(tm - mx <= 8.0f)) {      // wave-uniform; rare after warm-up
        const float mnew = fmaxf(mx, tm);
        const float sc = exp2f(mx - mnew);
        float scr[4];
#pragma unroll
        for (int r = 0; r < 4; ++r)
          scr[r] = __shfl(sc, (lane & 48) | (g4 * 4 + r));
#pragma unroll
        for (int nf = 0; nf < 4; ++nf)
#pragma unroll
          for (int r = 0; r < 4; ++r) o[nf][r] *= scr[r];
#pragma unroll
        for (int r = 0; r < 4; ++r) osum[r] *= scr[r];
        mx = mnew;
      }
#pragma unroll
      for (int c = 0; c < 4; ++c)
#pragma unroll
        for (int r = 0; r < 4; ++r)
          s[c][r] = exp2f(s[c][r] - mx);  // bounded by 2^8

      // ---- P -> PV A-fragments, in-lane (kappa ordering) ----
      bf16x8 ap0, ap1;
#pragma unroll
      for (int r = 0; r < 4; ++r) {
        ap0[r]     = f2bf(s[0][r]);
        ap0[4 + r] = f2bf(s[1][r]);
        ap1[r]     = f2bf(s[2][r]);
        ap1[4 + r] = f2bf(s[3][r]);
      }

      // L on the matrix pipe: osum += P x ones (both kappa halves)
      osum = __builtin_amdgcn_mfma_f32_16x16x32_bf16(ap0, ones8, osum, 0, 0, 0);
      osum = __builtin_amdgcn_mfma_f32_16x16x32_bf16(ap1, ones8, osum, 0, 0, 0);

      // ---- PV: o[q][d] += P V, keys in kappa order on both operands ----
#pragma unroll
      for (int nf = 0; nf < 4; ++nf) {
        const int d  = nf * 16 + l15;
        const int h3 = (2 * nf + (l15 >> 3)) & 7;   // (d>>3)&7
        bf16x8 vf0 = *(const bf16x8*)&VtC[d * PLD + ((g4 ^ h3) << 3)];
        bf16x8 vf1 = *(const bf16x8*)&VtC[d * PLD + (((g4 + 4) ^ h3) << 3)];
        o[nf] = __builtin_amdgcn_mfma_f32_16x16x32_bf16(ap0, vf0, o[nf], 0, 0, 0);
        o[nf] = __builtin_amdgcn_mfma_f32_16x16x32_bf16(ap1, vf1, o[nf], 0, 0, 0);
      }
    }

    if (it + 1 < ntp) {                   // write prefetched period into the other dbuf
      bf16_t* Ks0 = Ks + ((cur ^ 1) * 2 + 0) * KSB;
      bf16_t* Ks1 = Ks + ((cur ^ 1) * 2 + 1) * KSB;
      bf16_t* Vt0 = Vt + ((cur ^ 1) * 2 + 0) * VTB;
      bf16_t* Vt1 = Vt + ((cur ^ 1) * 2 + 1) * VTB;
      *(uint4*)&Ks0[skk * 64 + ksw] = kv0;
      *(uint4*)&Ks1[skk * 64 + ksw] = kv1;
      const bf16_t* vb0 = (const bf16_t*)&vv0;
      const bf16_t* vb1 = (const bf16_t*)&vv1;
#pragma unroll
      for (int i = 0; i < 8; ++i) {
        Vt0[(sd0 + i) * PLD + pos] = vb0[i];
        Vt1[(sd0 + i) * PLD + pos] = vb1[i];
      }
    }
    __syncthreads();
  }

  const int bb = bh / H_, hh = bh % H_;
  float il[4];
#pragma unroll
  for (int r = 0; r < 4; ++r)
    il[r] = 1.0f / osum[r];                // lane-local: osum[r] is L for q-row rowb+r
#pragma unroll
  for (int nf = 0; nf < 4; ++nf)
#pragma unroll
    for (int r = 0; r < 4; ++r) {
      const int row = rowb + r;
      y[(size_t)(bb * T_ + row) * C_ + hh * D_ + nf * 16 + l15] = f2bf(o[nf][r] * il[r]);
    }
}

// ---------------- GEMM2: out = y @ w_proj + b_proj (fp32 out) ----------------
// 1D grid + XCD swizzle (256 = 8 XCD x 32; one n-tile per XCD)
__global__ __launch_bounds__(256) void proj_gemm(const bf16_t* __restrict__ yin,
                                                 const bf16_t* __restrict__ wT,
                                                 const float* __restrict__ bias,
                                                 float* __restrict__ out) {
  __shared__ __align__(16) bf16_t smem[4 * GTILE];
  f32x4 acc[4][4];
  const int bid = blockIdx.x;
  const int swz = (bid & 7) * 32 + (bid >> 3);
  const int m0 = (swz & 31) * 128, n0 = (swz >> 5) * 128;
  gemm_core(yin, wT, m0, n0, smem, acc);

  const int t = threadIdx.x;
  const int lane = t & 63, w = t >> 6;
  const int wr = (w >> 1) * 64, wc = (w & 1) * 64;
  const int l15 = lane & 15, g4 = lane >> 4;
  const int ng = n0 + wc;
#pragma unroll
  for (int mi = 0; mi < 4; ++mi) {
    const int rowb = m0 + wr + mi * 16 + g4 * 4;
#pragma unroll
    for (int ni = 0; ni < 4; ++ni) {
      const int n = ng + ni * 16 + l15;
      const float b1 = bias[n];
#pragma unroll
      for (int r = 0; r < 4; ++r)
        out[(size_t)(rowb + r) * C_ + n] = acc[mi][ni][r] + b1;
    }
  }
}

// ---------------- launch ----------------
extern "C" void kernel_launch(void* const* d_in, const int* in_sizes, int n_in,
                              void* d_out, int out_size, void* d_ws, size_t ws_size,
                              hipStream_t stream) {
  (void)in_sizes; (void)n_in; (void)out_size; (void)ws_size;
  const float* x      = (const float*)d_in[0];
  const float* w_attn = (const float*)d_in[1];
  const float* b_attn = (const float*)d_in[2];
  const float* w_proj = (const float*)d_in[3];
  const float* b_proj = (const float*)d_in[4];
  float* out = (float*)d_out;

  char* ws = (char*)d_ws;
  bf16_t* wTa = (bf16_t*)ws;  ws += (size_t)NQKV_ * C_ * 2;          // 6 MB
  bf16_t* wTp = (bf16_t*)ws;  ws += (size_t)C_ * C_ * 2;             // 2 MB
  bf16_t* qb  = (bf16_t*)ws;  ws += (size_t)B_ * H_ * T_ * D_ * 2;   // 8 MB
  bf16_t* kb  = (bf16_t*)ws;  ws += (size_t)B_ * H_ * T_ * D_ * 2;   // 8 MB
  bf16_t* vb  = (bf16_t*)ws;  ws += (size_t)B_ * H_ * T_ * D_ * 2;   // 8 MB
  bf16_t* yb  = (bf16_t*)ws;  ws += (size_t)B_ * T_ * C_ * 2;        // 8 MB
  float2* rtab = (float2*)ws; ws += (size_t)T_ * 32 * sizeof(float2);// 0.5 MB
  // x_bf aliases yb: x_bf is consumed by qkv_gemm (dispatch 2) strictly before
  // attn_fwd (dispatch 3) writes yb. Stream-ordered, deterministic.
  bf16_t* x_bf = yb;

  // fused prep: 256 rope + 3072 tA + 1024 tP + 2048 convert = 6400 blocks
  prep_k<<<dim3(6400), 256, 0, stream>>>(rtab, w_attn, wTa, w_proj, wTp, x, x_bf);
  qkv_gemm<<<dim3((M_ / 128) * (NQKV_ / 384)), 512, 0, stream>>>(x_bf, wTa, b_attn, rtab, qb, kb, vb);
  attn_fwd<<<dim3(NQT2 * 32), 512, 0, stream>>>(qb, kb, vb, yb);
  proj_gemm<<<dim3((M_ / 128) * (C_ / 128)), 256, 0, stream>>>(yb, wTp, b_proj, out);
}